// Round 1
// baseline (727.966 us; speedup 1.0000x reference)
//
#include <hip/hip_runtime.h>
#include <math.h>

#define NND   32768   // total vertices (NN*BS)
#define HIDD  128
#define NHEAD 64
#define BSS   512
#define OUTC  3

// ---------------- CSR build ----------------
__global__ void count_kernel(const int* __restrict__ ei, int E, int* __restrict__ counts) {
    int j = blockIdx.x * 256 + threadIdx.x;
    int Etot = E + NND;
    if (j >= Etot) return;
    int dst = (j < E) ? ei[E + j] : (j - E);
    atomicAdd(&counts[dst], 1);
}

__global__ __launch_bounds__(1024) void scan_kernel(const int* __restrict__ counts,
                                                    int* __restrict__ off,
                                                    int* __restrict__ cursor) {
    __shared__ int sums[1024];
    int tid = threadIdx.x;
    int base = tid * 32;
    int tmp[32];
    int run = 0;
#pragma unroll
    for (int i = 0; i < 32; ++i) { int c = counts[base + i]; tmp[i] = run; run += c; }
    sums[tid] = run;
    __syncthreads();
    for (int d = 1; d < 1024; d <<= 1) {
        int v = (tid >= d) ? sums[tid - d] : 0;
        __syncthreads();
        sums[tid] += v;
        __syncthreads();
    }
    int ebase = (tid == 0) ? 0 : sums[tid - 1];
#pragma unroll
    for (int i = 0; i < 32; ++i) {
        int o = ebase + tmp[i];
        off[base + i]    = o;
        cursor[base + i] = o;
    }
    if (tid == 1023) off[NND] = sums[1023];
}

__global__ void fill_kernel(const int* __restrict__ ei, int E, int* __restrict__ cursor,
                            int* __restrict__ csr_src, int* __restrict__ csr_dst) {
    int j = blockIdx.x * 256 + threadIdx.x;
    int Etot = E + NND;
    if (j >= Etot) return;
    int src, dst;
    if (j < E) { src = ei[j]; dst = ei[E + j]; }
    else       { src = j - E; dst = j - E; }
    int pos = atomicAdd(&cursor[dst], 1);
    csr_src[pos] = src;
    csr_dst[pos] = dst;
}

// ---------------- feature transform: Hout[N][128] = X[N][K] @ W[K][128] ----------------
template <int K, int KT>
__global__ __launch_bounds__(256) void gemm_kernel(const float* __restrict__ X,
                                                   const float* __restrict__ W,
                                                   float* __restrict__ Hout) {
    __shared__ float Ws[KT * HIDD];   // k-tile of W
    __shared__ float Xs[K * 32];      // X tile, transposed [k][n_local]
    int tid = threadIdx.x;
    int n0 = blockIdx.x * 32;
    for (int i = tid; i < 32 * K; i += 256) {
        int n = i / K, k = i - n * K;
        Xs[k * 32 + n] = X[(size_t)(n0 + n) * K + k];
    }
    int cg = (tid & 31) * 4;   // channel base (0..124)
    int ng = (tid >> 5) * 4;   // node base   (0..28)
    float acc[4][4] = {};
    for (int kt = 0; kt < K; kt += KT) {
        __syncthreads();  // Xs ready (first iter) / previous compute done (later)
        for (int i = tid; i < KT * HIDD / 4; i += 256)
            ((float4*)Ws)[i] = ((const float4*)W)[(size_t)kt * (HIDD / 4) + i];
        __syncthreads();
#pragma unroll 4
        for (int k = 0; k < KT; ++k) {
            float4 wv = *(const float4*)&Ws[k * HIDD + cg];
            float4 xv = *(const float4*)&Xs[(kt + k) * 32 + ng];
            acc[0][0] += xv.x * wv.x; acc[0][1] += xv.x * wv.y; acc[0][2] += xv.x * wv.z; acc[0][3] += xv.x * wv.w;
            acc[1][0] += xv.y * wv.x; acc[1][1] += xv.y * wv.y; acc[1][2] += xv.y * wv.z; acc[1][3] += xv.y * wv.w;
            acc[2][0] += xv.z * wv.x; acc[2][1] += xv.z * wv.y; acc[2][2] += xv.z * wv.z; acc[2][3] += xv.z * wv.w;
            acc[3][0] += xv.w * wv.x; acc[3][1] += xv.w * wv.y; acc[3][2] += xv.w * wv.z; acc[3][3] += xv.w * wv.w;
        }
    }
#pragma unroll
    for (int i = 0; i < 4; ++i) {
        float4 r = make_float4(acc[i][0], acc[i][1], acc[i][2], acc[i][3]);
        *(float4*)&Hout[(size_t)(n0 + ng + i) * HIDD + cg] = r;
    }
}

// ---------------- per-node attention scalars ----------------
__global__ __launch_bounds__(256) void att_kernel(const float* __restrict__ H,
                                                  const float* __restrict__ att_src,
                                                  const float* __restrict__ att_dst,
                                                  float* __restrict__ a_s,
                                                  float* __restrict__ a_d) {
    int gw = (blockIdx.x * 256 + threadIdx.x) >> 6;
    int lane = threadIdx.x & 63;
    if (gw >= NND) return;
    float2 hv = *(const float2*)&H[(size_t)gw * HIDD + lane * 2];
    float2 as = *(const float2*)&att_src[lane * 2];
    float2 ad = *(const float2*)&att_dst[lane * 2];
    float ps = hv.x * as.x + hv.y * as.y;
    float pd = hv.x * ad.x + hv.y * ad.y;
#pragma unroll
    for (int o = 32; o; o >>= 1) { ps += __shfl_xor(ps, o); pd += __shfl_xor(pd, o); }
    if (lane == 0) { a_s[gw] = ps; a_d[gw] = pd; }
}

// ---------------- per-edge raw attention (leaky relu) ----------------
__global__ void edge_kernel(const int* __restrict__ csr_src, const int* __restrict__ csr_dst,
                            const float* __restrict__ a_s, const float* __restrict__ a_d,
                            float* __restrict__ evals, int Etot) {
    int j = blockIdx.x * 256 + threadIdx.x;
    if (j >= Etot) return;
    float e = a_s[csr_src[j]] + a_d[csr_dst[j]];
    evals[j] = (e > 0.f) ? e : 0.2f * e;
}

// ---------------- softmax-weighted aggregation (online softmax, wave per dst) ----------------
__global__ __launch_bounds__(256) void agg_kernel(const float* __restrict__ G,
                                                  const float* __restrict__ evals,
                                                  const int* __restrict__ csr_src,
                                                  const int* __restrict__ off,
                                                  const float* __restrict__ bias,
                                                  float* __restrict__ Hbuf,
                                                  int mode) {  // 0: relu write, 1: residual add
    int d = (blockIdx.x * 256 + threadIdx.x) >> 6;
    int lane = threadIdx.x & 63;
    if (d >= NND) return;
    int beg = off[d], end = off[d + 1];
    float m = -INFINITY, z = 0.f, ax = 0.f, ay = 0.f;
    for (int j = beg; j < end; ++j) {
        int s = csr_src[j];
        float e = evals[j];
        float2 hv = *(const float2*)&G[(size_t)s * HIDD + lane * 2];
        float nm = fmaxf(m, e);
        float sc = __expf(m - nm);   // first iter: exp(-inf)=0
        float p  = __expf(e - nm);
        z  = z  * sc + p;
        ax = ax * sc + p * hv.x;
        ay = ay * sc + p * hv.y;
        m = nm;
    }
    float inv = 1.f / (z + 1e-16f);
    float2 b = *(const float2*)&bias[lane * 2];
    float rx = ax * inv + b.x;
    float ry = ay * inv + b.y;
    float2* o = (float2*)&Hbuf[(size_t)d * HIDD + lane * 2];
    if (mode == 0) {
        *o = make_float2(fmaxf(rx, 0.f), fmaxf(ry, 0.f));
    } else {
        float2 old = *o;
        *o = make_float2(old.x + rx, old.y + ry);
    }
}

// ---------------- relu(layernorm) ----------------
__global__ __launch_bounds__(256) void ln_kernel(const float* __restrict__ H,
                                                 const float* __restrict__ gamma,
                                                 const float* __restrict__ beta,
                                                 float* __restrict__ T) {
    int n = (blockIdx.x * 256 + threadIdx.x) >> 6;
    int lane = threadIdx.x & 63;
    if (n >= NND) return;
    float2 hv = *(const float2*)&H[(size_t)n * HIDD + lane * 2];
    float s = hv.x + hv.y;
#pragma unroll
    for (int o = 32; o; o >>= 1) s += __shfl_xor(s, o);
    float mu = s * (1.f / HIDD);
    float dx = hv.x - mu, dy = hv.y - mu;
    float v = dx * dx + dy * dy;
#pragma unroll
    for (int o = 32; o; o >>= 1) v += __shfl_xor(v, o);
    float rs = rsqrtf(v * (1.f / HIDD) + 1e-5f);
    float2 g  = *(const float2*)&gamma[lane * 2];
    float2 b2 = *(const float2*)&beta[lane * 2];
    float tx = fmaxf(dx * rs * g.x + b2.x, 0.f);
    float ty = fmaxf(dy * rs * g.y + b2.y, 0.f);
    *(float2*)&T[(size_t)n * HIDD + lane * 2] = make_float2(tx, ty);
}

// ---------------- per-node-head predictor + softmax ----------------
__global__ __launch_bounds__(256) void pred_kernel(const float* __restrict__ T,
                                                   const float* __restrict__ W1p,
                                                   const float* __restrict__ W2p,
                                                   float* __restrict__ out) {
    __shared__ float W1s[HIDD * 64];  // 32 KB
    __shared__ float W2s[64 * OUTC];
    __shared__ float xr[4][HIDD];
    int head = blockIdx.y;
    int tid = threadIdx.x;
    const float* W1g = W1p + (size_t)head * HIDD * 64;
    for (int i = tid; i < HIDD * 64 / 4; i += 256)
        ((float4*)W1s)[i] = ((const float4*)W1g)[i];
    for (int i = tid; i < 64 * OUTC; i += 256)
        W2s[i] = W2p[(size_t)head * 64 * OUTC + i];
    __syncthreads();
    int wv = tid >> 6, lane = tid & 63;
    for (int it = 0; it < 16; ++it) {
        int row0 = blockIdx.x * 64 + it * 4;
        for (int i = tid; i < 4 * HIDD; i += 256)
            xr[i >> 7][i & 127] = T[(size_t)(head * BSS + row0 + (i >> 7)) * HIDD + (i & 127)];
        __syncthreads();
        int row = row0 + wv;
        float acc = 0.f;
#pragma unroll 8
        for (int c = 0; c < HIDD; ++c) acc += xr[wv][c] * W1s[c * 64 + lane];
        float t = fmaxf(acc, 0.f);
        float l0 = t * W2s[lane * OUTC + 0];
        float l1 = t * W2s[lane * OUTC + 1];
        float l2 = t * W2s[lane * OUTC + 2];
#pragma unroll
        for (int o = 32; o; o >>= 1) {
            l0 += __shfl_xor(l0, o); l1 += __shfl_xor(l1, o); l2 += __shfl_xor(l2, o);
        }
        if (lane == 0) {
            float mx = fmaxf(l0, fmaxf(l1, l2));
            float e0 = __expf(l0 - mx), e1 = __expf(l1 - mx), e2 = __expf(l2 - mx);
            float inv = 1.f / (e0 + e1 + e2);
            float* op = out + (size_t)(head * BSS + row) * OUTC;
            op[0] = e0 * inv; op[1] = e1 * inv; op[2] = e2 * inv;
        }
        __syncthreads();
    }
}

extern "C" void kernel_launch(void* const* d_in, const int* in_sizes, int n_in,
                              void* d_out, int out_size, void* d_ws, size_t ws_size,
                              hipStream_t stream) {
    const float* x        = (const float*)d_in[0];
    const int*   ei       = (const int*)d_in[1];
    const float* W0       = (const float*)d_in[2];
    const float* att_src0 = (const float*)d_in[3];
    const float* att_dst0 = (const float*)d_in[4];
    const float* bias0    = (const float*)d_in[5];
    const float* W_res    = (const float*)d_in[6];
    const float* as_res   = (const float*)d_in[7];
    const float* ad_res   = (const float*)d_in[8];
    const float* b_res    = (const float*)d_in[9];
    const float* gamma    = (const float*)d_in[10];
    const float* beta     = (const float*)d_in[11];
    const float* W1p      = (const float*)d_in[12];
    const float* W2p      = (const float*)d_in[13];
    float* out = (float*)d_out;

    int E = in_sizes[1] / 2;
    int Etot = E + NND;

    char* p = (char*)d_ws;
    auto alloc = [&](size_t bytes) { void* r = (void*)p; p += (bytes + 255) & ~(size_t)255; return r; };
    int*   counts  = (int*)alloc((size_t)NND * 4);
    int*   off     = (int*)alloc((size_t)(NND + 1) * 4);
    int*   cursor  = (int*)alloc((size_t)NND * 4);
    int*   csr_src = (int*)alloc((size_t)Etot * 4);
    int*   csr_dst = (int*)alloc((size_t)Etot * 4);
    float* evals   = (float*)alloc((size_t)Etot * 4);
    float* Hbuf    = (float*)alloc((size_t)NND * HIDD * 4);
    float* Tbuf    = (float*)alloc((size_t)NND * HIDD * 4);
    float* Gbuf    = (float*)alloc((size_t)NND * HIDD * 4);
    float* a_s     = (float*)alloc((size_t)NND * 4);
    float* a_d     = (float*)alloc((size_t)NND * 4);

    int egrid = (Etot + 255) / 256;

    // CSR build (edge structure shared by all 5 GAT layers)
    hipMemsetAsync(counts, 0, (size_t)NND * 4, stream);
    count_kernel<<<egrid, 256, 0, stream>>>(ei, E, counts);
    scan_kernel<<<1, 1024, 0, stream>>>(counts, off, cursor);
    fill_kernel<<<egrid, 256, 0, stream>>>(ei, E, cursor, csr_src, csr_dst);

    // layer 0: h = relu(GAT(x))
    gemm_kernel<32, 32><<<NND / 32, 256, 0, stream>>>(x, W0, Gbuf);
    att_kernel<<<NND / 4, 256, 0, stream>>>(Gbuf, att_src0, att_dst0, a_s, a_d);
    edge_kernel<<<egrid, 256, 0, stream>>>(csr_src, csr_dst, a_s, a_d, evals, Etot);
    agg_kernel<<<NND / 4, 256, 0, stream>>>(Gbuf, evals, csr_src, off, bias0, Hbuf, 0);

    // residual blocks: h = h + GAT(relu(LN(h)))
    for (int i = 0; i < 4; ++i) {
        ln_kernel<<<NND / 4, 256, 0, stream>>>(Hbuf, gamma + i * HIDD, beta + i * HIDD, Tbuf);
        gemm_kernel<128, 64><<<NND / 32, 256, 0, stream>>>(Tbuf, W_res + (size_t)i * HIDD * HIDD, Gbuf);
        att_kernel<<<NND / 4, 256, 0, stream>>>(Gbuf, as_res + i * HIDD, ad_res + i * HIDD, a_s, a_d);
        edge_kernel<<<egrid, 256, 0, stream>>>(csr_src, csr_dst, a_s, a_d, evals, Etot);
        agg_kernel<<<NND / 4, 256, 0, stream>>>(Gbuf, evals, csr_src, off, b_res + i * HIDD, Hbuf, 1);
    }

    // final norm + predictor heads
    ln_kernel<<<NND / 4, 256, 0, stream>>>(Hbuf, gamma, beta, Tbuf);
    pred_kernel<<<dim3(8, NHEAD), 256, 0, stream>>>(Tbuf, W1p, W2p, out);
}

// Round 2
// 498.995 us; speedup vs baseline: 1.4589x; 1.4589x over previous
//
#include <hip/hip_runtime.h>
#include <hip/hip_fp16.h>
#include <math.h>

#define NND   32768   // total vertices (NN*BS)
#define HIDD  128
#define NHEAD 64
#define BSS   512
#define OUTC  3

// ---------------- CSR build ----------------
__global__ void count_kernel(const int* __restrict__ ei, int E, int* __restrict__ counts) {
    int j = blockIdx.x * 256 + threadIdx.x;
    int Etot = E + NND;
    if (j >= Etot) return;
    int dst = (j < E) ? ei[E + j] : (j - E);
    atomicAdd(&counts[dst], 1);
}

__global__ __launch_bounds__(1024) void scan_kernel(const int* __restrict__ counts,
                                                    int* __restrict__ off,
                                                    int* __restrict__ cursor) {
    __shared__ int sums[1024];
    int tid = threadIdx.x;
    int base = tid * 32;
    int tmp[32];
    int run = 0;
#pragma unroll
    for (int i = 0; i < 32; ++i) { int c = counts[base + i]; tmp[i] = run; run += c; }
    sums[tid] = run;
    __syncthreads();
    for (int d = 1; d < 1024; d <<= 1) {
        int v = (tid >= d) ? sums[tid - d] : 0;
        __syncthreads();
        sums[tid] += v;
        __syncthreads();
    }
    int ebase = (tid == 0) ? 0 : sums[tid - 1];
#pragma unroll
    for (int i = 0; i < 32; ++i) {
        int o = ebase + tmp[i];
        off[base + i]    = o;
        cursor[base + i] = o;
    }
    if (tid == 1023) off[NND] = sums[1023];
}

__global__ void fill_kernel(const int* __restrict__ ei, int E, int* __restrict__ cursor,
                            int* __restrict__ csr_src) {
    int j = blockIdx.x * 256 + threadIdx.x;
    int Etot = E + NND;
    if (j >= Etot) return;
    int src, dst;
    if (j < E) { src = ei[j]; dst = ei[E + j]; }
    else       { src = j - E; dst = j - E; }
    int pos = atomicAdd(&cursor[dst], 1);
    csr_src[pos] = src;
}

// ---------------- feature transform + attention-scalar epilogue ----------------
// Gh[N][128] (fp16) = X[N][K] @ W[K][128];  a_s[n] = Gh_row . att_src;  a_d likewise
template <int K, int KT>
__global__ __launch_bounds__(256) void gemm_kernel(const float* __restrict__ X,
                                                   const float* __restrict__ W,
                                                   const float* __restrict__ att_src,
                                                   const float* __restrict__ att_dst,
                                                   __half* __restrict__ Gh,
                                                   float* __restrict__ a_s,
                                                   float* __restrict__ a_d) {
    __shared__ float Ws[KT * HIDD];   // k-tile of W
    __shared__ float Xs[K * 32];      // X tile, transposed [k][n_local]
    int tid = threadIdx.x;
    int n0 = blockIdx.x * 32;
    for (int i = tid; i < 32 * K; i += 256) {
        int n = i / K, k = i - n * K;
        Xs[k * 32 + n] = X[(size_t)(n0 + n) * K + k];
    }
    int cg = (tid & 31) * 4;   // channel base (0..124)
    int ng = (tid >> 5) * 4;   // node base   (0..28)
    float acc[4][4] = {};
    for (int kt = 0; kt < K; kt += KT) {
        __syncthreads();
        for (int i = tid; i < KT * HIDD / 4; i += 256)
            ((float4*)Ws)[i] = ((const float4*)W)[(size_t)kt * (HIDD / 4) + i];
        __syncthreads();
#pragma unroll 4
        for (int k = 0; k < KT; ++k) {
            float4 wv = *(const float4*)&Ws[k * HIDD + cg];
            float4 xv = *(const float4*)&Xs[(kt + k) * 32 + ng];
            acc[0][0] += xv.x * wv.x; acc[0][1] += xv.x * wv.y; acc[0][2] += xv.x * wv.z; acc[0][3] += xv.x * wv.w;
            acc[1][0] += xv.y * wv.x; acc[1][1] += xv.y * wv.y; acc[1][2] += xv.y * wv.z; acc[1][3] += xv.y * wv.w;
            acc[2][0] += xv.z * wv.x; acc[2][1] += xv.z * wv.y; acc[2][2] += xv.z * wv.z; acc[2][3] += xv.z * wv.w;
            acc[3][0] += xv.w * wv.x; acc[3][1] += xv.w * wv.y; acc[3][2] += xv.w * wv.z; acc[3][3] += xv.w * wv.w;
        }
    }
    // store fp16 rows + attention scalars
    float4 asv = *(const float4*)&att_src[cg];
    float4 adv = *(const float4*)&att_dst[cg];
#pragma unroll
    for (int i = 0; i < 4; ++i) {
        int n = n0 + ng + i;
        union { int2 i2; __half2 h2[2]; } u;
        u.h2[0] = __floats2half2_rn(acc[i][0], acc[i][1]);
        u.h2[1] = __floats2half2_rn(acc[i][2], acc[i][3]);
        *(int2*)&Gh[(size_t)n * HIDD + cg] = u.i2;
        float ps = acc[i][0]*asv.x + acc[i][1]*asv.y + acc[i][2]*asv.z + acc[i][3]*asv.w;
        float pd = acc[i][0]*adv.x + acc[i][1]*adv.y + acc[i][2]*adv.z + acc[i][3]*adv.w;
#pragma unroll
        for (int o = 16; o; o >>= 1) { ps += __shfl_xor(ps, o); pd += __shfl_xor(pd, o); }
        if ((tid & 31) == 0) { a_s[n] = ps; a_d[n] = pd; }
    }
}

// ---------------- fused: edge attn + online softmax + gather-agg + residual + relu(LN) ----------------
// one wave per dst node; lanes cooperatively stage 64 edges (src idx + softmax weight)
// in registers, then broadcast via shfl for the fp16 feature gather.
__global__ __launch_bounds__(256) void agg_kernel(const __half* __restrict__ Gh,
                                                  const float* __restrict__ a_s,
                                                  const float* __restrict__ a_dv,
                                                  const int* __restrict__ csr_src,
                                                  const int* __restrict__ off,
                                                  const float* __restrict__ bias,
                                                  const float* __restrict__ gamma,
                                                  const float* __restrict__ beta,
                                                  float* __restrict__ Hbuf,
                                                  float* __restrict__ Tbuf,
                                                  int mode) {  // 0: relu write, 1: residual add
    int d = (blockIdx.x * 256 + threadIdx.x) >> 6;
    int lane = threadIdx.x & 63;
    if (d >= NND) return;
    int beg = off[d], end = off[d + 1];
    float adv = a_dv[d];
    float m = -INFINITY, z = 0.f, accx = 0.f, accy = 0.f;
    for (int base = beg; base < end; base += 64) {
        int j = base + lane;
        int s = 0; float e = -INFINITY;
        if (j < end) {
            s = csr_src[j];
            float t = a_s[s] + adv;
            e = (t > 0.f) ? t : 0.2f * t;
        }
        float cm = e;
#pragma unroll
        for (int o = 32; o; o >>= 1) cm = fmaxf(cm, __shfl_xor(cm, o));
        float nm = fmaxf(m, cm);
        float sc = __expf(m - nm);      // first chunk: exp(-inf)=0
        float p = (j < end) ? __expf(e - nm) : 0.f;
        float cz = p;
#pragma unroll
        for (int o = 32; o; o >>= 1) cz += __shfl_xor(cz, o);
        z = z * sc + cz;
        accx *= sc; accy *= sc;
        m = nm;
        int cnt = end - base; if (cnt > 64) cnt = 64;
        int k = 0;
        for (; k + 1 < cnt; k += 2) {
            int   s0 = __shfl(s, k),     s1 = __shfl(s, k + 1);
            float p0 = __shfl(p, k);
            float p1 = __shfl(p, k + 1);
            float2 f0 = __half22float2(*(const __half2*)&Gh[(size_t)s0 * HIDD + lane * 2]);
            float2 f1 = __half22float2(*(const __half2*)&Gh[(size_t)s1 * HIDD + lane * 2]);
            accx += p0 * f0.x; accy += p0 * f0.y;
            accx += p1 * f1.x; accy += p1 * f1.y;
        }
        if (k < cnt) {
            int s0 = __shfl(s, k);
            float p0 = __shfl(p, k);
            float2 f0 = __half22float2(*(const __half2*)&Gh[(size_t)s0 * HIDD + lane * 2]);
            accx += p0 * f0.x; accy += p0 * f0.y;
        }
    }
    float inv = 1.f / (z + 1e-16f);
    float2 bv = *(const float2*)&bias[lane * 2];
    float rx = accx * inv + bv.x;
    float ry = accy * inv + bv.y;
    float hx, hy;
    if (mode == 0) {
        hx = fmaxf(rx, 0.f); hy = fmaxf(ry, 0.f);
    } else {
        float2 old = *(const float2*)&Hbuf[(size_t)d * HIDD + lane * 2];
        hx = old.x + rx; hy = old.y + ry;
    }
    *(float2*)&Hbuf[(size_t)d * HIDD + lane * 2] = make_float2(hx, hy);
    // fused relu(layernorm) -> Tbuf (input of next gemm / predictor)
    float sum = hx + hy;
#pragma unroll
    for (int o = 32; o; o >>= 1) sum += __shfl_xor(sum, o);
    float mu = sum * (1.f / HIDD);
    float dx = hx - mu, dy = hy - mu;
    float v = dx * dx + dy * dy;
#pragma unroll
    for (int o = 32; o; o >>= 1) v += __shfl_xor(v, o);
    float rs = rsqrtf(v * (1.f / HIDD) + 1e-5f);
    float2 g  = *(const float2*)&gamma[lane * 2];
    float2 b2 = *(const float2*)&beta[lane * 2];
    float tx = fmaxf(dx * rs * g.x + b2.x, 0.f);
    float ty = fmaxf(dy * rs * g.y + b2.y, 0.f);
    *(float2*)&Tbuf[(size_t)d * HIDD + lane * 2] = make_float2(tx, ty);
}

// ---------------- per-node-head predictor + softmax ----------------
__global__ __launch_bounds__(256) void pred_kernel(const float* __restrict__ T,
                                                   const float* __restrict__ W1p,
                                                   const float* __restrict__ W2p,
                                                   float* __restrict__ out) {
    __shared__ float W1s[HIDD * 64];  // 32 KB
    __shared__ float W2s[64 * OUTC];
    __shared__ float xr[4][HIDD];
    int head = blockIdx.y;
    int tid = threadIdx.x;
    const float* W1g = W1p + (size_t)head * HIDD * 64;
    for (int i = tid; i < HIDD * 64 / 4; i += 256)
        ((float4*)W1s)[i] = ((const float4*)W1g)[i];
    for (int i = tid; i < 64 * OUTC; i += 256)
        W2s[i] = W2p[(size_t)head * 64 * OUTC + i];
    __syncthreads();
    int wv = tid >> 6, lane = tid & 63;
    for (int it = 0; it < 16; ++it) {
        int row0 = blockIdx.x * 64 + it * 4;
        for (int i = tid; i < 4 * HIDD; i += 256)
            xr[i >> 7][i & 127] = T[(size_t)(head * BSS + row0 + (i >> 7)) * HIDD + (i & 127)];
        __syncthreads();
        int row = row0 + wv;
        float acc = 0.f;
#pragma unroll 8
        for (int c = 0; c < HIDD; ++c) acc += xr[wv][c] * W1s[c * 64 + lane];
        float t = fmaxf(acc, 0.f);
        float l0 = t * W2s[lane * OUTC + 0];
        float l1 = t * W2s[lane * OUTC + 1];
        float l2 = t * W2s[lane * OUTC + 2];
#pragma unroll
        for (int o = 32; o; o >>= 1) {
            l0 += __shfl_xor(l0, o); l1 += __shfl_xor(l1, o); l2 += __shfl_xor(l2, o);
        }
        if (lane == 0) {
            float mx = fmaxf(l0, fmaxf(l1, l2));
            float e0 = __expf(l0 - mx), e1 = __expf(l1 - mx), e2 = __expf(l2 - mx);
            float inv = 1.f / (e0 + e1 + e2);
            float* op = out + (size_t)(head * BSS + row) * OUTC;
            op[0] = e0 * inv; op[1] = e1 * inv; op[2] = e2 * inv;
        }
        __syncthreads();
    }
}

extern "C" void kernel_launch(void* const* d_in, const int* in_sizes, int n_in,
                              void* d_out, int out_size, void* d_ws, size_t ws_size,
                              hipStream_t stream) {
    const float* x        = (const float*)d_in[0];
    const int*   ei       = (const int*)d_in[1];
    const float* W0       = (const float*)d_in[2];
    const float* att_src0 = (const float*)d_in[3];
    const float* att_dst0 = (const float*)d_in[4];
    const float* bias0    = (const float*)d_in[5];
    const float* W_res    = (const float*)d_in[6];
    const float* as_res   = (const float*)d_in[7];
    const float* ad_res   = (const float*)d_in[8];
    const float* b_res    = (const float*)d_in[9];
    const float* gamma    = (const float*)d_in[10];
    const float* beta     = (const float*)d_in[11];
    const float* W1p      = (const float*)d_in[12];
    const float* W2p      = (const float*)d_in[13];
    float* out = (float*)d_out;

    int E = in_sizes[1] / 2;
    int Etot = E + NND;

    char* p = (char*)d_ws;
    auto alloc = [&](size_t bytes) { void* r = (void*)p; p += (bytes + 255) & ~(size_t)255; return r; };
    int*    counts  = (int*)alloc((size_t)NND * 4);
    int*    off     = (int*)alloc((size_t)(NND + 1) * 4);
    int*    cursor  = (int*)alloc((size_t)NND * 4);
    int*    csr_src = (int*)alloc((size_t)Etot * 4);
    __half* Gh      = (__half*)alloc((size_t)NND * HIDD * 2);
    float*  Hbuf    = (float*)alloc((size_t)NND * HIDD * 4);
    float*  Tbuf    = (float*)alloc((size_t)NND * HIDD * 4);
    float*  a_s     = (float*)alloc((size_t)NND * 4);
    float*  a_d     = (float*)alloc((size_t)NND * 4);

    int egrid = (Etot + 255) / 256;

    // CSR build (edge structure shared by all 5 GAT layers)
    hipMemsetAsync(counts, 0, (size_t)NND * 4, stream);
    count_kernel<<<egrid, 256, 0, stream>>>(ei, E, counts);
    scan_kernel<<<1, 1024, 0, stream>>>(counts, off, cursor);
    fill_kernel<<<egrid, 256, 0, stream>>>(ei, E, cursor, csr_src);

    // layer 0: h = relu(GAT(x));  T = relu(LN_0(h))
    gemm_kernel<32, 32><<<NND / 32, 256, 0, stream>>>(x, W0, att_src0, att_dst0, Gh, a_s, a_d);
    agg_kernel<<<NND / 4, 256, 0, stream>>>(Gh, a_s, a_d, csr_src, off, bias0,
                                            gamma, beta, Hbuf, Tbuf, 0);

    // residual blocks: h = h + GAT(T);  T = relu(LN_{i+1 or 0}(h))
    for (int i = 0; i < 4; ++i) {
        gemm_kernel<128, 64><<<NND / 32, 256, 0, stream>>>(Tbuf, W_res + (size_t)i * HIDD * HIDD,
                                                           as_res + i * HIDD, ad_res + i * HIDD,
                                                           Gh, a_s, a_d);
        int gi = (i < 3) ? (i + 1) : 0;   // final LN uses gamma[0]/beta[0]
        agg_kernel<<<NND / 4, 256, 0, stream>>>(Gh, a_s, a_d, csr_src, off, b_res + i * HIDD,
                                                gamma + gi * HIDD, beta + gi * HIDD, Hbuf, Tbuf, 1);
    }

    // predictor heads on final T
    pred_kernel<<<dim3(8, NHEAD), 256, 0, stream>>>(Tbuf, W1p, W2p, out);
}

// Round 3
// 363.296 us; speedup vs baseline: 2.0038x; 1.3735x over previous
//
#include <hip/hip_runtime.h>
#include <math.h>

#define NND   32768   // total vertices (NN*BS)
#define HIDD  128
#define NHEAD 64
#define BSS   512
#define OUTC  3

typedef _Float16 half_t;
typedef __attribute__((ext_vector_type(8))) _Float16 half8;  // MFMA A/B frag (4 VGPRs)
typedef __attribute__((ext_vector_type(4))) float f32x4;     // MFMA C/D frag

// ---------------- CSR build ----------------
__global__ void count_kernel(const int* __restrict__ ei, int E, int* __restrict__ counts) {
    int j = blockIdx.x * 256 + threadIdx.x;
    int Etot = E + NND;
    if (j >= Etot) return;
    int dst = (j < E) ? ei[E + j] : (j - E);
    atomicAdd(&counts[dst], 1);
}

__global__ __launch_bounds__(1024) void scan_kernel(const int* __restrict__ counts,
                                                    int* __restrict__ off,
                                                    int* __restrict__ cursor) {
    __shared__ int sums[1024];
    int tid = threadIdx.x;
    int base = tid * 32;
    int tmp[32];
    int run = 0;
#pragma unroll
    for (int i = 0; i < 32; ++i) { int c = counts[base + i]; tmp[i] = run; run += c; }
    sums[tid] = run;
    __syncthreads();
    for (int d = 1; d < 1024; d <<= 1) {
        int v = (tid >= d) ? sums[tid - d] : 0;
        __syncthreads();
        sums[tid] += v;
        __syncthreads();
    }
    int ebase = (tid == 0) ? 0 : sums[tid - 1];
#pragma unroll
    for (int i = 0; i < 32; ++i) {
        int o = ebase + tmp[i];
        off[base + i]    = o;
        cursor[base + i] = o;
    }
    if (tid == 1023) off[NND] = sums[1023];
}

__global__ void fill_kernel(const int* __restrict__ ei, int E, int* __restrict__ cursor,
                            int* __restrict__ csr_src) {
    int j = blockIdx.x * 256 + threadIdx.x;
    int Etot = E + NND;
    if (j >= Etot) return;
    int src, dst;
    if (j < E) { src = ei[j]; dst = ei[E + j]; }
    else       { src = j - E; dst = j - E; }
    int pos = atomicAdd(&cursor[dst], 1);
    csr_src[pos] = src;
}

// ---------------- layer-0 feature transform (K=32, fp32 VALU) ----------------
template <int K, int KT>
__global__ __launch_bounds__(256) void gemm_kernel(const float* __restrict__ X,
                                                   const float* __restrict__ W,
                                                   const float* __restrict__ att_src,
                                                   const float* __restrict__ att_dst,
                                                   half_t* __restrict__ Gh,
                                                   float* __restrict__ a_s,
                                                   float* __restrict__ a_d) {
    __shared__ float Ws[KT * HIDD];
    __shared__ float Xs[K * 32];
    int tid = threadIdx.x;
    int n0 = blockIdx.x * 32;
    for (int i = tid; i < 32 * K; i += 256) {
        int n = i / K, k = i - n * K;
        Xs[k * 32 + n] = X[(size_t)(n0 + n) * K + k];
    }
    int cg = (tid & 31) * 4;
    int ng = (tid >> 5) * 4;
    float acc[4][4] = {};
    for (int kt = 0; kt < K; kt += KT) {
        __syncthreads();
        for (int i = tid; i < KT * HIDD / 4; i += 256)
            ((float4*)Ws)[i] = ((const float4*)W)[(size_t)kt * (HIDD / 4) + i];
        __syncthreads();
#pragma unroll 4
        for (int k = 0; k < KT; ++k) {
            float4 wv = *(const float4*)&Ws[k * HIDD + cg];
            float4 xv = *(const float4*)&Xs[(kt + k) * 32 + ng];
            acc[0][0] += xv.x * wv.x; acc[0][1] += xv.x * wv.y; acc[0][2] += xv.x * wv.z; acc[0][3] += xv.x * wv.w;
            acc[1][0] += xv.y * wv.x; acc[1][1] += xv.y * wv.y; acc[1][2] += xv.y * wv.z; acc[1][3] += xv.y * wv.w;
            acc[2][0] += xv.z * wv.x; acc[2][1] += xv.z * wv.y; acc[2][2] += xv.z * wv.z; acc[2][3] += xv.z * wv.w;
            acc[3][0] += xv.w * wv.x; acc[3][1] += xv.w * wv.y; acc[3][2] += xv.w * wv.z; acc[3][3] += xv.w * wv.w;
        }
    }
    float4 asv = *(const float4*)&att_src[cg];
    float4 adv = *(const float4*)&att_dst[cg];
#pragma unroll
    for (int i = 0; i < 4; ++i) {
        int n = n0 + ng + i;
        union { int2 i2; half_t h[4]; } u;
        u.h[0] = (half_t)acc[i][0]; u.h[1] = (half_t)acc[i][1];
        u.h[2] = (half_t)acc[i][2]; u.h[3] = (half_t)acc[i][3];
        *(int2*)&Gh[(size_t)n * HIDD + cg] = u.i2;
        float ps = acc[i][0]*asv.x + acc[i][1]*asv.y + acc[i][2]*asv.z + acc[i][3]*asv.w;
        float pd = acc[i][0]*adv.x + acc[i][1]*adv.y + acc[i][2]*adv.z + acc[i][3]*adv.w;
#pragma unroll
        for (int o = 16; o; o >>= 1) { ps += __shfl_xor(ps, o); pd += __shfl_xor(pd, o); }
        if ((tid & 31) == 0) { a_s[n] = ps; a_d[n] = pd; }
    }
}

// ---------------- residual-layer transform, MFMA fp16: Gh = Th @ W, + attn scalars ----------------
__global__ __launch_bounds__(256) void gemm_mfma_kernel(const half_t* __restrict__ Th,
                                                        const float* __restrict__ W,
                                                        const float* __restrict__ att_src,
                                                        const float* __restrict__ att_dst,
                                                        half_t* __restrict__ Gh,
                                                        float* __restrict__ a_s,
                                                        float* __restrict__ a_d) {
    __shared__ half_t Wt[128 * 136];   // W^T fp16, [n][k] pad 136 (16B-aligned rows)
    __shared__ half_t OutT[64 * HIDD]; // block output tile, fp16
    int tid = threadIdx.x;
    int n0 = blockIdx.x * 64;
    {   // stage Wt[n][k] = (half)W[k][n]; coalesced global reads (row-major k rows)
        int n = tid & 127;
        int kk0 = (tid >> 7) * 32;   // half2 index base
        for (int kk = 0; kk < 32; ++kk) {
            int k2 = (kk0 + kk) * 2;
            union { unsigned u; half_t h[2]; } cv;
            cv.h[0] = (half_t)W[(size_t)k2 * HIDD + n];
            cv.h[1] = (half_t)W[(size_t)(k2 + 1) * HIDD + n];
            *(unsigned*)&Wt[n * 136 + k2] = cv.u;
        }
    }
    int wv = tid >> 6, lane = tid & 63;
    int q = lane >> 4, r15 = lane & 15;
    // A fragments direct from global (independent of Wt staging)
    half8 afrag[4];
    int nodeA = n0 + wv * 16 + r15;
#pragma unroll
    for (int s = 0; s < 4; ++s)
        afrag[s] = *(const half8*)&Th[(size_t)nodeA * HIDD + s * 32 + q * 8];
    __syncthreads();
    f32x4 acc[8];
#pragma unroll
    for (int ct = 0; ct < 8; ++ct) {
        f32x4 c = {0.f, 0.f, 0.f, 0.f};
        int n = ct * 16 + r15;
#pragma unroll
        for (int s = 0; s < 4; ++s) {
            half8 b = *(const half8*)&Wt[n * 136 + s * 32 + q * 8];
            c = __builtin_amdgcn_mfma_f32_16x16x32_f16(afrag[s], b, c, 0, 0, 0);
        }
        acc[ct] = c;
    }
    // attention scalars via quad reduction + OutT scatter
    float ps[4] = {0.f,0.f,0.f,0.f}, pd[4] = {0.f,0.f,0.f,0.f};
#pragma unroll
    for (int ct = 0; ct < 8; ++ct) {
        float av = att_src[ct * 16 + r15];
        float bv = att_dst[ct * 16 + r15];
#pragma unroll
        for (int r = 0; r < 4; ++r) {
            float v = acc[ct][r];
            ps[r] += v * av;
            pd[r] += v * bv;
            OutT[(wv * 16 + q * 4 + r) * HIDD + ct * 16 + r15] = (half_t)v;
        }
    }
#pragma unroll
    for (int o = 8; o; o >>= 1) {
#pragma unroll
        for (int r = 0; r < 4; ++r) { ps[r] += __shfl_xor(ps[r], o); pd[r] += __shfl_xor(pd[r], o); }
    }
    if (r15 == 0) {
#pragma unroll
        for (int r = 0; r < 4; ++r) {
            int node = n0 + wv * 16 + q * 4 + r;
            a_s[node] = ps[r];
            a_d[node] = pd[r];
        }
    }
    __syncthreads();
    // coalesced copy OutT -> Gh (contiguous 16 KB region)
    const int4* srcp = (const int4*)OutT;
    int4* dstp = (int4*)&Gh[(size_t)n0 * HIDD];
    for (int i = tid; i < 64 * HIDD * 2 / 16; i += 256)
        dstp[i] = srcp[i];
}

// ---------------- fused: edge softmax + quad-vectorized gather-agg + residual + relu(LN) ----------------
__global__ __launch_bounds__(256) void agg_kernel(const half_t* __restrict__ Gh,
                                                  const float* __restrict__ a_s,
                                                  const float* __restrict__ a_dv,
                                                  const int* __restrict__ csr_src,
                                                  const int* __restrict__ off,
                                                  const float* __restrict__ bias,
                                                  const float* __restrict__ gamma,
                                                  const float* __restrict__ beta,
                                                  float* __restrict__ Hbuf,
                                                  half_t* __restrict__ Th,
                                                  int mode) {  // 0: relu write, 1: residual add
    int d = (blockIdx.x * 256 + threadIdx.x) >> 6;
    int lane = threadIdx.x & 63;
    if (d >= NND) return;
    int q = lane >> 4, r15 = lane & 15;
    int beg = off[d], end = off[d + 1];
    float adv = a_dv[d];
    float m = -INFINITY, z = 0.f;
    float acc[8] = {0.f,0.f,0.f,0.f,0.f,0.f,0.f,0.f};  // chs r15*8 .. r15*8+7 (per quad)
    for (int base = beg; base < end; base += 64) {
        int j = base + lane;
        int s = 0; float e = -INFINITY;
        if (j < end) {
            s = csr_src[j];
            float t = a_s[s] + adv;
            e = (t > 0.f) ? t : 0.2f * t;
        }
        float cm = e;
#pragma unroll
        for (int o = 32; o; o >>= 1) cm = fmaxf(cm, __shfl_xor(cm, o));
        float nm = fmaxf(m, cm);
        float sc = __expf(m - nm);      // first chunk: exp(-inf)=0
        float p = (j < end) ? __expf(e - nm) : 0.f;
        float cz = p;
#pragma unroll
        for (int o = 32; o; o >>= 1) cz += __shfl_xor(cz, o);
        z = z * sc + cz;
#pragma unroll
        for (int i = 0; i < 8; ++i) acc[i] *= sc;
        m = nm;
        int cnt = end - base; if (cnt > 64) cnt = 64;
        // quad gathers: 16 lanes x 16B per edge, 8 edges in flight
        for (int k4 = 0; k4 < cnt; k4 += 8) {
            int i0 = k4 + q, i1 = k4 + 4 + q;   // <= 63 always; slots >= cnt have p=0, s=0
            int   s0 = __shfl(s, i0);
            float p0 = __shfl(p, i0);
            int   s1 = __shfl(s, i1);
            float p1 = __shfl(p, i1);
            half8 h0 = *(const half8*)&Gh[(size_t)s0 * HIDD + r15 * 8];
            half8 h1 = *(const half8*)&Gh[(size_t)s1 * HIDD + r15 * 8];
#pragma unroll
            for (int i = 0; i < 8; ++i) acc[i] += p0 * (float)h0[i];
#pragma unroll
            for (int i = 0; i < 8; ++i) acc[i] += p1 * (float)h1[i];
        }
    }
    // cross-quad reduction (all quads end with full sums, replicated)
#pragma unroll
    for (int i = 0; i < 8; ++i) {
        acc[i] += __shfl_xor(acc[i], 16);
        acc[i] += __shfl_xor(acc[i], 32);
    }
    float inv = 1.f / (z + 1e-16f);
    float4 b0 = *(const float4*)&bias[r15 * 8];
    float4 b1 = *(const float4*)&bias[r15 * 8 + 4];
    float h[8];
    h[0] = acc[0]*inv + b0.x; h[1] = acc[1]*inv + b0.y; h[2] = acc[2]*inv + b0.z; h[3] = acc[3]*inv + b0.w;
    h[4] = acc[4]*inv + b1.x; h[5] = acc[5]*inv + b1.y; h[6] = acc[6]*inv + b1.z; h[7] = acc[7]*inv + b1.w;
    if (mode == 0) {
#pragma unroll
        for (int i = 0; i < 8; ++i) h[i] = fmaxf(h[i], 0.f);
    } else {
        float4 o0 = *(const float4*)&Hbuf[(size_t)d * HIDD + r15 * 8];
        float4 o1 = *(const float4*)&Hbuf[(size_t)d * HIDD + r15 * 8 + 4];
        h[0] += o0.x; h[1] += o0.y; h[2] += o0.z; h[3] += o0.w;
        h[4] += o1.x; h[5] += o1.y; h[6] += o1.z; h[7] += o1.w;
    }
    // fused relu(layernorm) -> Th fp16
    float sum = 0.f;
#pragma unroll
    for (int i = 0; i < 8; ++i) sum += h[i];
#pragma unroll
    for (int o = 8; o; o >>= 1) sum += __shfl_xor(sum, o);
    float mu = sum * (1.f / HIDD);
    float var = 0.f;
#pragma unroll
    for (int i = 0; i < 8; ++i) { float dx = h[i] - mu; var += dx * dx; }
#pragma unroll
    for (int o = 8; o; o >>= 1) var += __shfl_xor(var, o);
    float rs = rsqrtf(var * (1.f / HIDD) + 1e-5f);
    float4 g0 = *(const float4*)&gamma[r15 * 8];
    float4 g1 = *(const float4*)&gamma[r15 * 8 + 4];
    float4 bb0 = *(const float4*)&beta[r15 * 8];
    float4 bb1 = *(const float4*)&beta[r15 * 8 + 4];
    float gg[8] = {g0.x,g0.y,g0.z,g0.w,g1.x,g1.y,g1.z,g1.w};
    float be[8] = {bb0.x,bb0.y,bb0.z,bb0.w,bb1.x,bb1.y,bb1.z,bb1.w};
    if (q == 0) {
        float4 w0 = make_float4(h[0], h[1], h[2], h[3]);
        float4 w1 = make_float4(h[4], h[5], h[6], h[7]);
        *(float4*)&Hbuf[(size_t)d * HIDD + r15 * 8] = w0;
        *(float4*)&Hbuf[(size_t)d * HIDD + r15 * 8 + 4] = w1;
        union { int4 v; half_t hh[8]; } u;
#pragma unroll
        for (int i = 0; i < 8; ++i)
            u.hh[i] = (half_t)fmaxf((h[i] - mu) * rs * gg[i] + be[i], 0.f);
        *(int4*)&Th[(size_t)d * HIDD + r15 * 8] = u.v;
    }
}

// ---------------- per-node-head predictor, MFMA + fused W2/softmax ----------------
__global__ __launch_bounds__(256) void pred_kernel(const half_t* __restrict__ Th,
                                                   const float* __restrict__ W1p,
                                                   const float* __restrict__ W2p,
                                                   float* __restrict__ out) {
    __shared__ half_t W1t[64 * 136];   // W1^T fp16 [n][k]
    __shared__ float W2s[64 * OUTC];
    int tid = threadIdx.x;
    int head = blockIdx.x >> 2;
    int part = blockIdx.x & 3;
    const float* W1g = W1p + (size_t)head * HIDD * 64;
    {
        int n = tid & 63;
        int kk0 = (tid >> 6) * 16;
        for (int kk = 0; kk < 16; ++kk) {
            int k2 = (kk0 + kk) * 2;
            union { unsigned u; half_t h[2]; } cv;
            cv.h[0] = (half_t)W1g[(size_t)k2 * 64 + n];
            cv.h[1] = (half_t)W1g[(size_t)(k2 + 1) * 64 + n];
            *(unsigned*)&W1t[n * 136 + k2] = cv.u;
        }
    }
    if (tid < 64 * OUTC) W2s[tid] = W2p[(size_t)head * 64 * OUTC + tid];
    __syncthreads();
    int wv = tid >> 6, lane = tid & 63;
    int q = lane >> 4, r15 = lane & 15;
#pragma unroll
    for (int t16 = 0; t16 < 2; ++t16) {
        int rowbase = part * 128 + wv * 32 + t16 * 16;
        int nodeA = head * BSS + rowbase + r15;
        half8 afrag[4];
#pragma unroll
        for (int s = 0; s < 4; ++s)
            afrag[s] = *(const half8*)&Th[(size_t)nodeA * HIDD + s * 32 + q * 8];
        float lg[3][4];
#pragma unroll
        for (int o = 0; o < 3; ++o)
#pragma unroll
            for (int r = 0; r < 4; ++r) lg[o][r] = 0.f;
#pragma unroll
        for (int ct = 0; ct < 4; ++ct) {
            f32x4 c = {0.f, 0.f, 0.f, 0.f};
#pragma unroll
            for (int s = 0; s < 4; ++s) {
                half8 b = *(const half8*)&W1t[(ct * 16 + r15) * 136 + s * 32 + q * 8];
                c = __builtin_amdgcn_mfma_f32_16x16x32_f16(afrag[s], b, c, 0, 0, 0);
            }
            float w2a = W2s[(ct * 16 + r15) * OUTC + 0];
            float w2b = W2s[(ct * 16 + r15) * OUTC + 1];
            float w2c = W2s[(ct * 16 + r15) * OUTC + 2];
#pragma unroll
            for (int r = 0; r < 4; ++r) {
                float t = fmaxf(c[r], 0.f);
                lg[0][r] += t * w2a;
                lg[1][r] += t * w2b;
                lg[2][r] += t * w2c;
            }
        }
#pragma unroll
        for (int o = 8; o; o >>= 1)
#pragma unroll
            for (int oo = 0; oo < 3; ++oo)
#pragma unroll
                for (int r = 0; r < 4; ++r) lg[oo][r] += __shfl_xor(lg[oo][r], o);
        if (r15 == 0) {
#pragma unroll
            for (int r = 0; r < 4; ++r) {
                int row = rowbase + q * 4 + r;
                float l0 = lg[0][r], l1 = lg[1][r], l2 = lg[2][r];
                float mx = fmaxf(l0, fmaxf(l1, l2));
                float e0 = __expf(l0 - mx), e1 = __expf(l1 - mx), e2 = __expf(l2 - mx);
                float inv = 1.f / (e0 + e1 + e2);
                float* op = out + (size_t)(head * BSS + row) * OUTC;
                op[0] = e0 * inv; op[1] = e1 * inv; op[2] = e2 * inv;
            }
        }
    }
}

extern "C" void kernel_launch(void* const* d_in, const int* in_sizes, int n_in,
                              void* d_out, int out_size, void* d_ws, size_t ws_size,
                              hipStream_t stream) {
    const float* x        = (const float*)d_in[0];
    const int*   ei       = (const int*)d_in[1];
    const float* W0       = (const float*)d_in[2];
    const float* att_src0 = (const float*)d_in[3];
    const float* att_dst0 = (const float*)d_in[4];
    const float* bias0    = (const float*)d_in[5];
    const float* W_res    = (const float*)d_in[6];
    const float* as_res   = (const float*)d_in[7];
    const float* ad_res   = (const float*)d_in[8];
    const float* b_res    = (const float*)d_in[9];
    const float* gamma    = (const float*)d_in[10];
    const float* beta     = (const float*)d_in[11];
    const float* W1p      = (const float*)d_in[12];
    const float* W2p      = (const float*)d_in[13];
    float* out = (float*)d_out;

    int E = in_sizes[1] / 2;
    int Etot = E + NND;

    char* p = (char*)d_ws;
    auto alloc = [&](size_t bytes) { void* r = (void*)p; p += (bytes + 255) & ~(size_t)255; return r; };
    int*    counts  = (int*)alloc((size_t)NND * 4);
    int*    off     = (int*)alloc((size_t)(NND + 1) * 4);
    int*    cursor  = (int*)alloc((size_t)NND * 4);
    int*    csr_src = (int*)alloc((size_t)Etot * 4);
    half_t* Gh      = (half_t*)alloc((size_t)NND * HIDD * 2);
    half_t* Th      = (half_t*)alloc((size_t)NND * HIDD * 2);
    float*  Hbuf    = (float*)alloc((size_t)NND * HIDD * 4);
    float*  a_s     = (float*)alloc((size_t)NND * 4);
    float*  a_d     = (float*)alloc((size_t)NND * 4);

    int egrid = (Etot + 255) / 256;

    // CSR build (edge structure shared by all 5 GAT layers)
    hipMemsetAsync(counts, 0, (size_t)NND * 4, stream);
    count_kernel<<<egrid, 256, 0, stream>>>(ei, E, counts);
    scan_kernel<<<1, 1024, 0, stream>>>(counts, off, cursor);
    fill_kernel<<<egrid, 256, 0, stream>>>(ei, E, cursor, csr_src);

    // layer 0: h = relu(GAT(x));  Th = relu(LN_0(h)) fp16
    gemm_kernel<32, 32><<<NND / 32, 256, 0, stream>>>(x, W0, att_src0, att_dst0, Gh, a_s, a_d);
    agg_kernel<<<NND / 4, 256, 0, stream>>>(Gh, a_s, a_d, csr_src, off, bias0,
                                            gamma, beta, Hbuf, Th, 0);

    // residual blocks: h = h + GAT(Th);  Th = relu(LN(h)) fp16
    for (int i = 0; i < 4; ++i) {
        gemm_mfma_kernel<<<NND / 64, 256, 0, stream>>>(Th, W_res + (size_t)i * HIDD * HIDD,
                                                       as_res + i * HIDD, ad_res + i * HIDD,
                                                       Gh, a_s, a_d);
        int gi = (i < 3) ? (i + 1) : 0;   // final LN uses gamma[0]/beta[0]
        agg_kernel<<<NND / 4, 256, 0, stream>>>(Gh, a_s, a_d, csr_src, off, b_res + i * HIDD,
                                                gamma + gi * HIDD, beta + gi * HIDD, Hbuf, Th, 1);
    }

    // predictor heads on final Th
    pred_kernel<<<dim3(NHEAD * 4), 256, 0, stream>>>(Th, W1p, W2p, out);
}

// Round 4
// 329.791 us; speedup vs baseline: 2.2074x; 1.1016x over previous
//
#include <hip/hip_runtime.h>
#include <math.h>

#define NND   32768   // total vertices (NN*BS)
#define HIDD  128
#define NHEAD 64
#define BSS   512
#define OUTC  3

typedef _Float16 half_t;
typedef __attribute__((ext_vector_type(8))) _Float16 half8;  // MFMA A/B frag (4 VGPRs)
typedef __attribute__((ext_vector_type(4))) float f32x4;     // MFMA C/D frag

// ---------------- CSR build ----------------
// pass 1: per-dst counts + per-edge rank (position within its dst bucket)
__global__ void count_kernel(const int* __restrict__ ei, int E,
                             int* __restrict__ counts, int* __restrict__ rank) {
    int j = blockIdx.x * 256 + threadIdx.x;
    int Etot = E + NND;
    if (j >= Etot) return;
    int dst = (j < E) ? ei[E + j] : (j - E);
    rank[j] = atomicAdd(&counts[dst], 1);
}

__global__ __launch_bounds__(1024) void scan_kernel(const int* __restrict__ counts,
                                                    int* __restrict__ off) {
    __shared__ int sums[1024];
    int tid = threadIdx.x;
    int base = tid * 32;
    int tmp[32];
    int run = 0;
#pragma unroll
    for (int i = 0; i < 8; ++i) {
        int4 c4 = *(const int4*)&counts[base + i * 4];
        tmp[i*4+0] = run; run += c4.x;
        tmp[i*4+1] = run; run += c4.y;
        tmp[i*4+2] = run; run += c4.z;
        tmp[i*4+3] = run; run += c4.w;
    }
    sums[tid] = run;
    __syncthreads();
    for (int d = 1; d < 1024; d <<= 1) {
        int v = (tid >= d) ? sums[tid - d] : 0;
        __syncthreads();
        sums[tid] += v;
        __syncthreads();
    }
    int ebase = (tid == 0) ? 0 : sums[tid - 1];
#pragma unroll
    for (int i = 0; i < 32; ++i) off[base + i] = ebase + tmp[i];
    if (tid == 1023) off[NND] = sums[1023];
}

__global__ void fill_kernel(const int* __restrict__ ei, int E,
                            const int* __restrict__ off, const int* __restrict__ rank,
                            int* __restrict__ csr_src) {
    int j = blockIdx.x * 256 + threadIdx.x;
    int Etot = E + NND;
    if (j >= Etot) return;
    int src, dst;
    if (j < E) { src = ei[j]; dst = ei[E + j]; }
    else       { src = j - E; dst = j - E; }
    csr_src[off[dst] + rank[j]] = src;
}

// ---------------- weight prep: fp32 -> transposed fp16, once per launch ----------------
// blocks 0..63   : W_res[4][128k][128n] -> Wh[4][n][k]      (16 32x32 tiles/layer)
// blocks 64..575 : W1p[64][128k][64n]   -> W1h[64][n][k]    (8 tiles/head)
__global__ __launch_bounds__(256) void prep_kernel(const float* __restrict__ W_res,
                                                   const float* __restrict__ W1p,
                                                   half_t* __restrict__ Wh,
                                                   half_t* __restrict__ W1h) {
    __shared__ float tile[32][33];
    int b = blockIdx.x;
    const float* src; half_t* dst; int srcld, k0, n0;
    if (b < 64) {
        int l = b >> 4, t = b & 15;
        k0 = (t >> 2) * 32; n0 = (t & 3) * 32;
        src = W_res + (size_t)l * 128 * 128; srcld = 128;
        dst = Wh + (size_t)l * 128 * 128;
    } else {
        int bb = b - 64; int head = bb >> 3, t = bb & 7;
        k0 = (t >> 1) * 32; n0 = (t & 1) * 32;
        src = W1p + (size_t)head * 128 * 64; srcld = 64;
        dst = W1h + (size_t)head * 64 * 128;
    }
    int c = threadIdx.x & 31, r0 = threadIdx.x >> 5;
#pragma unroll
    for (int i = 0; i < 4; ++i) {
        int r = r0 + i * 8;
        tile[r][c] = src[(size_t)(k0 + r) * srcld + n0 + c];
    }
    __syncthreads();
#pragma unroll
    for (int i = 0; i < 4; ++i) {
        int rr = r0 + i * 8;
        dst[(size_t)(n0 + rr) * 128 + k0 + c] = (half_t)tile[c][rr];  // dst[n][k]=src[k][n]
    }
}

// ---------------- layer-0 feature transform (K=32, fp32 VALU) ----------------
template <int K, int KT>
__global__ __launch_bounds__(256) void gemm_kernel(const float* __restrict__ X,
                                                   const float* __restrict__ W,
                                                   const float* __restrict__ att_src,
                                                   const float* __restrict__ att_dst,
                                                   half_t* __restrict__ Gh,
                                                   float* __restrict__ a_s,
                                                   float* __restrict__ a_d) {
    __shared__ float Ws[KT * HIDD];
    __shared__ float Xs[K * 32];
    int tid = threadIdx.x;
    int n0 = blockIdx.x * 32;
    for (int i = tid; i < 32 * K; i += 256) {
        int n = i / K, k = i - n * K;
        Xs[k * 32 + n] = X[(size_t)(n0 + n) * K + k];
    }
    int cg = (tid & 31) * 4;
    int ng = (tid >> 5) * 4;
    float acc[4][4] = {};
    for (int kt = 0; kt < K; kt += KT) {
        __syncthreads();
        for (int i = tid; i < KT * HIDD / 4; i += 256)
            ((float4*)Ws)[i] = ((const float4*)W)[(size_t)kt * (HIDD / 4) + i];
        __syncthreads();
#pragma unroll 4
        for (int k = 0; k < KT; ++k) {
            float4 wv = *(const float4*)&Ws[k * HIDD + cg];
            float4 xv = *(const float4*)&Xs[(kt + k) * 32 + ng];
            acc[0][0] += xv.x * wv.x; acc[0][1] += xv.x * wv.y; acc[0][2] += xv.x * wv.z; acc[0][3] += xv.x * wv.w;
            acc[1][0] += xv.y * wv.x; acc[1][1] += xv.y * wv.y; acc[1][2] += xv.y * wv.z; acc[1][3] += xv.y * wv.w;
            acc[2][0] += xv.z * wv.x; acc[2][1] += xv.z * wv.y; acc[2][2] += xv.z * wv.z; acc[2][3] += xv.z * wv.w;
            acc[3][0] += xv.w * wv.x; acc[3][1] += xv.w * wv.y; acc[3][2] += xv.w * wv.z; acc[3][3] += xv.w * wv.w;
        }
    }
    float4 asv = *(const float4*)&att_src[cg];
    float4 adv = *(const float4*)&att_dst[cg];
#pragma unroll
    for (int i = 0; i < 4; ++i) {
        int n = n0 + ng + i;
        union { int2 i2; half_t h[4]; } u;
        u.h[0] = (half_t)acc[i][0]; u.h[1] = (half_t)acc[i][1];
        u.h[2] = (half_t)acc[i][2]; u.h[3] = (half_t)acc[i][3];
        *(int2*)&Gh[(size_t)n * HIDD + cg] = u.i2;
        float ps = acc[i][0]*asv.x + acc[i][1]*asv.y + acc[i][2]*asv.z + acc[i][3]*asv.w;
        float pd = acc[i][0]*adv.x + acc[i][1]*adv.y + acc[i][2]*adv.z + acc[i][3]*adv.w;
#pragma unroll
        for (int o = 16; o; o >>= 1) { ps += __shfl_xor(ps, o); pd += __shfl_xor(pd, o); }
        if ((tid & 31) == 0) { a_s[n] = ps; a_d[n] = pd; }
    }
}

// ---------------- residual-layer transform, MFMA fp16: Gh = Th @ W, + attn scalars ----------------
__global__ __launch_bounds__(256) void gemm_mfma_kernel(const half_t* __restrict__ Th,
                                                        const half_t* __restrict__ Whl,  // [n][k] fp16
                                                        const float* __restrict__ att_src,
                                                        const float* __restrict__ att_dst,
                                                        half_t* __restrict__ Gh,
                                                        float* __restrict__ a_s,
                                                        float* __restrict__ a_d) {
    __shared__ half_t Wt[128 * 136];   // padded copy of Whl
    __shared__ half_t OutT[64 * HIDD]; // block output tile, fp16
    int tid = threadIdx.x;
    int n0 = blockIdx.x * 64;
    // stage Wt from precomputed fp16 W^T: coalesced int4 loads
    for (int i = tid; i < 128 * 16; i += 256) {
        int n = i >> 4, c = i & 15;
        *(int4*)&Wt[n * 136 + c * 8] = *(const int4*)&Whl[(size_t)n * 128 + c * 8];
    }
    int wv = tid >> 6, lane = tid & 63;
    int q = lane >> 4, r15 = lane & 15;
    half8 afrag[4];
    int nodeA = n0 + wv * 16 + r15;
#pragma unroll
    for (int s = 0; s < 4; ++s)
        afrag[s] = *(const half8*)&Th[(size_t)nodeA * HIDD + s * 32 + q * 8];
    __syncthreads();
    f32x4 acc[8];
#pragma unroll
    for (int ct = 0; ct < 8; ++ct) {
        f32x4 c = {0.f, 0.f, 0.f, 0.f};
        int n = ct * 16 + r15;
#pragma unroll
        for (int s = 0; s < 4; ++s) {
            half8 b = *(const half8*)&Wt[n * 136 + s * 32 + q * 8];
            c = __builtin_amdgcn_mfma_f32_16x16x32_f16(afrag[s], b, c, 0, 0, 0);
        }
        acc[ct] = c;
    }
    float ps[4] = {0.f,0.f,0.f,0.f}, pd[4] = {0.f,0.f,0.f,0.f};
#pragma unroll
    for (int ct = 0; ct < 8; ++ct) {
        float av = att_src[ct * 16 + r15];
        float bv = att_dst[ct * 16 + r15];
#pragma unroll
        for (int r = 0; r < 4; ++r) {
            float v = acc[ct][r];
            ps[r] += v * av;
            pd[r] += v * bv;
            OutT[(wv * 16 + q * 4 + r) * HIDD + ct * 16 + r15] = (half_t)v;
        }
    }
#pragma unroll
    for (int o = 8; o; o >>= 1) {
#pragma unroll
        for (int r = 0; r < 4; ++r) { ps[r] += __shfl_xor(ps[r], o); pd[r] += __shfl_xor(pd[r], o); }
    }
    if (r15 == 0) {
#pragma unroll
        for (int r = 0; r < 4; ++r) {
            int node = n0 + wv * 16 + q * 4 + r;
            a_s[node] = ps[r];
            a_d[node] = pd[r];
        }
    }
    __syncthreads();
    const int4* srcp = (const int4*)OutT;
    int4* dstp = (int4*)&Gh[(size_t)n0 * HIDD];
    for (int i = tid; i < 64 * HIDD * 2 / 16; i += 256)
        dstp[i] = srcp[i];
}

// ---------------- fused: edge softmax (unshifted exp) + quad gather-agg + residual + relu(LN) --------
__global__ __launch_bounds__(256) void agg_kernel(const half_t* __restrict__ Gh,
                                                  const float* __restrict__ a_s,
                                                  const float* __restrict__ a_dv,
                                                  const int* __restrict__ csr_src,
                                                  const int* __restrict__ off,
                                                  const float* __restrict__ bias,
                                                  const float* __restrict__ gamma,
                                                  const float* __restrict__ beta,
                                                  float* __restrict__ Hbuf,
                                                  half_t* __restrict__ Th,
                                                  int mode) {  // 0: relu write, 1: residual add
    int d = (blockIdx.x * 256 + threadIdx.x) >> 6;
    int lane = threadIdx.x & 63;
    if (d >= NND) return;
    int q = lane >> 4, r15 = lane & 15;
    int beg = off[d], end = off[d + 1];
    float adv = a_dv[d];
    float pz = 0.f;
    float acc[8] = {0.f,0.f,0.f,0.f,0.f,0.f,0.f,0.f};  // chs r15*8 .. r15*8+7 (per quad)
    for (int base = beg; base < end; base += 64) {
        int j = base + lane;
        int s = 0; float p = 0.f;
        if (j < end) {
            s = csr_src[j];
            float t = a_s[s] + adv;
            t = (t > 0.f) ? t : 0.2f * t;
            p = __expf(t);           // |t| <~ 10: no overflow; max-shift unnecessary
        }
        pz += p;
        int cnt = end - base; if (cnt > 64) cnt = 64;
        // 4 quad-gathers (16 edges) in flight; k4 <= 48 so all shfl indices <= 63;
        // slots >= cnt carry p=0 (harmless row-0 loads, L1-resident)
        for (int k4 = 0; k4 < cnt; k4 += 16) {
            int   s0 = __shfl(s, k4 + q);       float p0 = __shfl(p, k4 + q);
            int   s1 = __shfl(s, k4 + 4 + q);   float p1 = __shfl(p, k4 + 4 + q);
            int   s2 = __shfl(s, k4 + 8 + q);   float p2 = __shfl(p, k4 + 8 + q);
            int   s3 = __shfl(s, k4 + 12 + q);  float p3 = __shfl(p, k4 + 12 + q);
            half8 h0 = *(const half8*)&Gh[(size_t)s0 * HIDD + r15 * 8];
            half8 h1 = *(const half8*)&Gh[(size_t)s1 * HIDD + r15 * 8];
            half8 h2 = *(const half8*)&Gh[(size_t)s2 * HIDD + r15 * 8];
            half8 h3 = *(const half8*)&Gh[(size_t)s3 * HIDD + r15 * 8];
#pragma unroll
            for (int i = 0; i < 8; ++i) acc[i] += p0 * (float)h0[i];
#pragma unroll
            for (int i = 0; i < 8; ++i) acc[i] += p1 * (float)h1[i];
#pragma unroll
            for (int i = 0; i < 8; ++i) acc[i] += p2 * (float)h2[i];
#pragma unroll
            for (int i = 0; i < 8; ++i) acc[i] += p3 * (float)h3[i];
        }
    }
    // single end-of-loop reductions
#pragma unroll
    for (int o = 32; o; o >>= 1) pz += __shfl_xor(pz, o);
#pragma unroll
    for (int i = 0; i < 8; ++i) {
        acc[i] += __shfl_xor(acc[i], 16);
        acc[i] += __shfl_xor(acc[i], 32);
    }
    float inv = 1.f / (pz + 1e-16f);
    float4 b0 = *(const float4*)&bias[r15 * 8];
    float4 b1 = *(const float4*)&bias[r15 * 8 + 4];
    float h[8];
    h[0] = acc[0]*inv + b0.x; h[1] = acc[1]*inv + b0.y; h[2] = acc[2]*inv + b0.z; h[3] = acc[3]*inv + b0.w;
    h[4] = acc[4]*inv + b1.x; h[5] = acc[5]*inv + b1.y; h[6] = acc[6]*inv + b1.z; h[7] = acc[7]*inv + b1.w;
    if (mode == 0) {
#pragma unroll
        for (int i = 0; i < 8; ++i) h[i] = fmaxf(h[i], 0.f);
    } else {
        float4 o0 = *(const float4*)&Hbuf[(size_t)d * HIDD + r15 * 8];
        float4 o1 = *(const float4*)&Hbuf[(size_t)d * HIDD + r15 * 8 + 4];
        h[0] += o0.x; h[1] += o0.y; h[2] += o0.z; h[3] += o0.w;
        h[4] += o1.x; h[5] += o1.y; h[6] += o1.z; h[7] += o1.w;
    }
    // fused relu(layernorm) -> Th fp16
    float sum = 0.f;
#pragma unroll
    for (int i = 0; i < 8; ++i) sum += h[i];
#pragma unroll
    for (int o = 8; o; o >>= 1) sum += __shfl_xor(sum, o);
    float mu = sum * (1.f / HIDD);
    float var = 0.f;
#pragma unroll
    for (int i = 0; i < 8; ++i) { float dx = h[i] - mu; var += dx * dx; }
#pragma unroll
    for (int o = 8; o; o >>= 1) var += __shfl_xor(var, o);
    float rs = rsqrtf(var * (1.f / HIDD) + 1e-5f);
    float4 g0 = *(const float4*)&gamma[r15 * 8];
    float4 g1 = *(const float4*)&gamma[r15 * 8 + 4];
    float4 bb0 = *(const float4*)&beta[r15 * 8];
    float4 bb1 = *(const float4*)&beta[r15 * 8 + 4];
    float gg[8] = {g0.x,g0.y,g0.z,g0.w,g1.x,g1.y,g1.z,g1.w};
    float be[8] = {bb0.x,bb0.y,bb0.z,bb0.w,bb1.x,bb1.y,bb1.z,bb1.w};
    if (q == 0) {
        *(float4*)&Hbuf[(size_t)d * HIDD + r15 * 8]     = make_float4(h[0], h[1], h[2], h[3]);
        *(float4*)&Hbuf[(size_t)d * HIDD + r15 * 8 + 4] = make_float4(h[4], h[5], h[6], h[7]);
        union { int4 v; half_t hh[8]; } u;
#pragma unroll
        for (int i = 0; i < 8; ++i)
            u.hh[i] = (half_t)fmaxf((h[i] - mu) * rs * gg[i] + be[i], 0.f);
        *(int4*)&Th[(size_t)d * HIDD + r15 * 8] = u.v;
    }
}

// ---------------- per-node-head predictor, MFMA + fused W2/softmax ----------------
__global__ __launch_bounds__(256) void pred_kernel(const half_t* __restrict__ Th,
                                                   const half_t* __restrict__ W1h,  // [head][n][k] fp16
                                                   const float* __restrict__ W2p,
                                                   float* __restrict__ out) {
    __shared__ half_t W1t[64 * 136];
    __shared__ float W2s[64 * OUTC];
    int tid = threadIdx.x;
    int head = blockIdx.x >> 2;
    int part = blockIdx.x & 3;
    const half_t* W1g = W1h + (size_t)head * 64 * 128;
    for (int i = tid; i < 64 * 16; i += 256) {
        int n = i >> 4, c = i & 15;
        *(int4*)&W1t[n * 136 + c * 8] = *(const int4*)&W1g[(size_t)n * 128 + c * 8];
    }
    if (tid < 64 * OUTC) W2s[tid] = W2p[(size_t)head * 64 * OUTC + tid];
    __syncthreads();
    int wv = tid >> 6, lane = tid & 63;
    int q = lane >> 4, r15 = lane & 15;
#pragma unroll
    for (int t16 = 0; t16 < 2; ++t16) {
        int rowbase = part * 128 + wv * 32 + t16 * 16;
        int nodeA = head * BSS + rowbase + r15;
        half8 afrag[4];
#pragma unroll
        for (int s = 0; s < 4; ++s)
            afrag[s] = *(const half8*)&Th[(size_t)nodeA * HIDD + s * 32 + q * 8];
        float lg[3][4];
#pragma unroll
        for (int o = 0; o < 3; ++o)
#pragma unroll
            for (int r = 0; r < 4; ++r) lg[o][r] = 0.f;
#pragma unroll
        for (int ct = 0; ct < 4; ++ct) {
            f32x4 c = {0.f, 0.f, 0.f, 0.f};
#pragma unroll
            for (int s = 0; s < 4; ++s) {
                half8 b = *(const half8*)&W1t[(ct * 16 + r15) * 136 + s * 32 + q * 8];
                c = __builtin_amdgcn_mfma_f32_16x16x32_f16(afrag[s], b, c, 0, 0, 0);
            }
            float w2a = W2s[(ct * 16 + r15) * OUTC + 0];
            float w2b = W2s[(ct * 16 + r15) * OUTC + 1];
            float w2c = W2s[(ct * 16 + r15) * OUTC + 2];
#pragma unroll
            for (int r = 0; r < 4; ++r) {
                float t = fmaxf(c[r], 0.f);
                lg[0][r] += t * w2a;
                lg[1][r] += t * w2b;
                lg[2][r] += t * w2c;
            }
        }
#pragma unroll
        for (int o = 8; o; o >>= 1)
#pragma unroll
            for (int oo = 0; oo < 3; ++oo)
#pragma unroll
                for (int r = 0; r < 4; ++r) lg[oo][r] += __shfl_xor(lg[oo][r], o);
        if (r15 == 0) {
#pragma unroll
            for (int r = 0; r < 4; ++r) {
                int row = rowbase + q * 4 + r;
                float l0 = lg[0][r], l1 = lg[1][r], l2 = lg[2][r];
                float mx = fmaxf(l0, fmaxf(l1, l2));
                float e0 = __expf(l0 - mx), e1 = __expf(l1 - mx), e2 = __expf(l2 - mx);
                float inv = 1.f / (e0 + e1 + e2);
                float* op = out + (size_t)(head * BSS + row) * OUTC;
                op[0] = e0 * inv; op[1] = e1 * inv; op[2] = e2 * inv;
            }
        }
    }
}

extern "C" void kernel_launch(void* const* d_in, const int* in_sizes, int n_in,
                              void* d_out, int out_size, void* d_ws, size_t ws_size,
                              hipStream_t stream) {
    const float* x        = (const float*)d_in[0];
    const int*   ei       = (const int*)d_in[1];
    const float* W0       = (const float*)d_in[2];
    const float* att_src0 = (const float*)d_in[3];
    const float* att_dst0 = (const float*)d_in[4];
    const float* bias0    = (const float*)d_in[5];
    const float* W_res    = (const float*)d_in[6];
    const float* as_res   = (const float*)d_in[7];
    const float* ad_res   = (const float*)d_in[8];
    const float* b_res    = (const float*)d_in[9];
    const float* gamma    = (const float*)d_in[10];
    const float* beta     = (const float*)d_in[11];
    const float* W1p      = (const float*)d_in[12];
    const float* W2p      = (const float*)d_in[13];
    float* out = (float*)d_out;

    int E = in_sizes[1] / 2;
    int Etot = E + NND;

    char* p = (char*)d_ws;
    auto alloc = [&](size_t bytes) { void* r = (void*)p; p += (bytes + 255) & ~(size_t)255; return r; };
    int*    counts  = (int*)alloc((size_t)NND * 4);
    int*    off     = (int*)alloc((size_t)(NND + 1) * 4);
    int*    rank    = (int*)alloc((size_t)Etot * 4);
    int*    csr_src = (int*)alloc((size_t)Etot * 4);
    half_t* Gh      = (half_t*)alloc((size_t)NND * HIDD * 2);
    half_t* Th      = (half_t*)alloc((size_t)NND * HIDD * 2);
    float*  Hbuf    = (float*)alloc((size_t)NND * HIDD * 4);
    float*  a_s     = (float*)alloc((size_t)NND * 4);
    float*  a_d     = (float*)alloc((size_t)NND * 4);
    half_t* Wh      = (half_t*)alloc((size_t)4 * HIDD * HIDD * 2);
    half_t* W1h     = (half_t*)alloc((size_t)NHEAD * 64 * HIDD * 2);

    int egrid = (Etot + 255) / 256;

    // CSR build + weight prep
    hipMemsetAsync(counts, 0, (size_t)NND * 4, stream);
    count_kernel<<<egrid, 256, 0, stream>>>(ei, E, counts, rank);
    scan_kernel<<<1, 1024, 0, stream>>>(counts, off);
    fill_kernel<<<egrid, 256, 0, stream>>>(ei, E, off, rank, csr_src);
    prep_kernel<<<576, 256, 0, stream>>>(W_res, W1p, Wh, W1h);

    // layer 0: h = relu(GAT(x));  Th = relu(LN_0(h)) fp16
    gemm_kernel<32, 32><<<NND / 32, 256, 0, stream>>>(x, W0, att_src0, att_dst0, Gh, a_s, a_d);
    agg_kernel<<<NND / 4, 256, 0, stream>>>(Gh, a_s, a_d, csr_src, off, bias0,
                                            gamma, beta, Hbuf, Th, 0);

    // residual blocks: h = h + GAT(Th);  Th = relu(LN(h)) fp16
    for (int i = 0; i < 4; ++i) {
        gemm_mfma_kernel<<<NND / 64, 256, 0, stream>>>(Th, Wh + (size_t)i * HIDD * HIDD,
                                                       as_res + i * HIDD, ad_res + i * HIDD,
                                                       Gh, a_s, a_d);
        int gi = (i < 3) ? (i + 1) : 0;   // final LN uses gamma[0]/beta[0]
        agg_kernel<<<NND / 4, 256, 0, stream>>>(Gh, a_s, a_d, csr_src, off, b_res + i * HIDD,
                                                gamma + gi * HIDD, beta + gi * HIDD, Hbuf, Th, 1);
    }

    // predictor heads on final Th
    pred_kernel<<<dim3(NHEAD * 4), 256, 0, stream>>>(Th, W1h, W2p, out);
}

// Round 5
// 302.508 us; speedup vs baseline: 2.4064x; 1.0902x over previous
//
#include <hip/hip_runtime.h>
#include <math.h>

#define NND   32768
#define HIDD  128
#define NHEAD 64
#define BSS   512
#define OUTC  3

typedef _Float16 half_t;
typedef __attribute__((ext_vector_type(8))) _Float16 half8;  // MFMA A/B frag
typedef __attribute__((ext_vector_type(4))) float f32x4;     // MFMA C/D frag

// ---------------- prep: weight transposes, w_s/w_d projections, x cast, counts zero ----
__global__ __launch_bounds__(256) void prep_kernel(const float* __restrict__ W0,
        const float* __restrict__ W_res, const float* __restrict__ W1p,
        const float* __restrict__ as0, const float* __restrict__ ad0,
        const float* __restrict__ as_res, const float* __restrict__ ad_res,
        const float* __restrict__ x,
        half_t* __restrict__ Wh, half_t* __restrict__ W1h, half_t* __restrict__ W0t,
        float* __restrict__ wvec, half_t* __restrict__ xh, int* __restrict__ counts) {
    int b = blockIdx.x, tid = threadIdx.x;
    if (b < 64) {            // W_res[l][128k][128n] -> Wh[l][n][k] fp16
        __shared__ float tile[32][33];
        int l = b >> 4, t = b & 15;
        int k0 = (t >> 2) * 32, n0 = (t & 3) * 32;
        const float* src = W_res + (size_t)l * 128 * 128;
        half_t* dst = Wh + (size_t)l * 128 * 128;
        int c = tid & 31, r0 = tid >> 5;
#pragma unroll
        for (int i = 0; i < 4; ++i) tile[r0 + i * 8][c] = src[(size_t)(k0 + r0 + i * 8) * 128 + n0 + c];
        __syncthreads();
#pragma unroll
        for (int i = 0; i < 4; ++i) dst[(size_t)(n0 + r0 + i * 8) * 128 + k0 + c] = (half_t)tile[c][r0 + i * 8];
    } else if (b < 576) {    // W1p[h][128k][64n] -> W1h[h][n][k] fp16
        __shared__ float tile[32][33];
        int bb = b - 64, head = bb >> 3, t = bb & 7;
        int k0 = (t >> 1) * 32, n0 = (t & 1) * 32;
        const float* src = W1p + (size_t)head * 128 * 64;
        half_t* dst = W1h + (size_t)head * 64 * 128;
        int c = tid & 31, r0 = tid >> 5;
#pragma unroll
        for (int i = 0; i < 4; ++i) tile[r0 + i * 8][c] = src[(size_t)(k0 + r0 + i * 8) * 64 + n0 + c];
        __syncthreads();
#pragma unroll
        for (int i = 0; i < 4; ++i) dst[(size_t)(n0 + r0 + i * 8) * 128 + k0 + c] = (half_t)tile[c][r0 + i * 8];
    } else if (b == 576) {   // W0[32k][128n] -> W0t[n][k] fp16
        __shared__ float t0[32][129];
        for (int i = tid; i < 4096; i += 256) t0[i >> 7][i & 127] = W0[i];
        __syncthreads();
        for (int i = tid; i < 4096; i += 256) { int n = i >> 5, k = i & 31; W0t[n * 32 + k] = (half_t)t0[k][n]; }
    } else if (b == 577) {   // w_s[l][k] = sum_n W_l[k][n]*att_src_l[n]; w_d likewise (wvec+640)
        for (int task = tid; task < 1088; task += 256) {
            const float* row; const float* att; int slot, sd;
            if (task < 64) {
                int k = task >> 1; sd = task & 1;
                row = W0 + k * 128; att = sd ? ad0 : as0; slot = k;
            } else {
                int tt = task - 64; int l = 1 + tt / 256; int r = tt % 256;
                int k = r >> 1; sd = r & 1;
                row = W_res + (size_t)(l - 1) * 16384 + k * 128;
                att = (sd ? ad_res : as_res) + (l - 1) * 128;
                slot = l * 128 + k;
            }
            float s = 0.f;
            for (int n = 0; n < 128; ++n) s += row[n] * att[n];
            (sd ? wvec + 640 : wvec)[slot] = s;
        }
    } else if (b < 1090) {   // x fp32 -> xh fp16
        int b2 = b - 578;
        const float* xs = x + (size_t)b2 * 64 * 32;
        half_t* xd = xh + (size_t)b2 * 64 * 32;
        for (int i = tid; i < 1024; i += 256) {
            float2 v = ((const float2*)xs)[i];
            union { unsigned u; half_t h[2]; } cv;
            cv.h[0] = (half_t)v.x; cv.h[1] = (half_t)v.y;
            ((unsigned*)xd)[i] = cv.u;
        }
    } else {                 // zero counts
        int b3 = b - 1090;
        ((int4*)counts)[b3 * 256 + tid] = make_int4(0, 0, 0, 0);
    }
}

// ---------------- layer-0 attention scalars: a_s0[n] = x[n] . w_s0 ----------------
__global__ __launch_bounds__(256) void a0_kernel(const half_t* __restrict__ xh,
                                                 const float* __restrict__ wvec,
                                                 float* __restrict__ a_s, float* __restrict__ a_d) {
    __shared__ float ws0[32], wd0[32];
    int tid = threadIdx.x;
    if (tid < 32) { ws0[tid] = wvec[tid]; wd0[tid] = wvec[640 + tid]; }
    __syncthreads();
    int g = blockIdx.x * 256 + tid;
    int node = g >> 2, part = g & 3;
    half8 xv = *(const half8*)&xh[(size_t)node * 32 + part * 8];
    float s = 0.f, d2 = 0.f;
#pragma unroll
    for (int j = 0; j < 8; ++j) { float f = (float)xv[j]; s += f * ws0[part * 8 + j]; d2 += f * wd0[part * 8 + j]; }
    s += __shfl_xor(s, 1); s += __shfl_xor(s, 2);
    d2 += __shfl_xor(d2, 1); d2 += __shfl_xor(d2, 2);
    if (part == 0) { a_s[node] = s; a_d[node] = d2; }
}

// ---------------- CSR build ----------------
__global__ void count_kernel(const int* __restrict__ ei, int E,
                             int* __restrict__ counts, int* __restrict__ rank) {
    int j = blockIdx.x * 256 + threadIdx.x;
    int Etot = E + NND;
    if (j >= Etot) return;
    int dst = (j < E) ? ei[E + j] : (j - E);
    rank[j] = atomicAdd(&counts[dst], 1);
}

__global__ __launch_bounds__(1024) void scan_kernel(const int* __restrict__ counts,
                                                    int* __restrict__ off) {
    __shared__ int sums[1024];
    int tid = threadIdx.x;
    int base = tid * 32;
    int tmp[32];
    int run = 0;
#pragma unroll
    for (int i = 0; i < 8; ++i) {
        int4 c4 = *(const int4*)&counts[base + i * 4];
        tmp[i*4+0] = run; run += c4.x;
        tmp[i*4+1] = run; run += c4.y;
        tmp[i*4+2] = run; run += c4.z;
        tmp[i*4+3] = run; run += c4.w;
    }
    sums[tid] = run;
    __syncthreads();
    for (int d = 1; d < 1024; d <<= 1) {
        int v = (tid >= d) ? sums[tid - d] : 0;
        __syncthreads();
        sums[tid] += v;
        __syncthreads();
    }
    int ebase = (tid == 0) ? 0 : sums[tid - 1];
#pragma unroll
    for (int i = 0; i < 32; ++i) off[base + i] = ebase + tmp[i];
    if (tid == 1023) off[NND] = sums[1023];
}

__global__ void fill_kernel(const int* __restrict__ ei, int E,
                            const int* __restrict__ off, const int* __restrict__ rank,
                            int* __restrict__ csr_src) {
    int j = blockIdx.x * 256 + threadIdx.x;
    int Etot = E + NND;
    if (j >= Etot) return;
    int src, dst;
    if (j < E) { src = ei[j]; dst = ei[E + j]; }
    else       { src = j - E; dst = j - E; }
    csr_src[off[dst] + rank[j]] = src;
}

// ---------------- layer-0 aggregation over x (32ch): P0[d] = sum alpha * xh[src] -------
__global__ __launch_bounds__(256) void agg0_kernel(const half_t* __restrict__ xh,
        const float* __restrict__ a_s, const float* __restrict__ a_dv,
        const int* __restrict__ csr_src, const int* __restrict__ off,
        half_t* __restrict__ P) {
    int d = (blockIdx.x * 256 + threadIdx.x) >> 6;
    int lane = threadIdx.x & 63;
    int q = lane >> 4, r15 = lane & 15;
    int beg = off[d], end = off[d + 1];
    float adv = a_dv[d];
    float pz = 0.f, a0 = 0.f, a1 = 0.f;
    for (int base = beg; base < end; base += 64) {
        int j = base + lane;
        int s = 0; float p = 0.f;
        if (j < end) {
            s = csr_src[j];
            float t = a_s[s] + adv;
            t = (t > 0.f) ? t : 0.2f * t;
            p = __expf(t);
        }
        pz += p;
        int cnt = end - base; if (cnt > 64) cnt = 64;
        int full = cnt & ~15;
        int k4 = 0;
        for (; k4 < full; k4 += 16) {
            int s0 = __shfl(s, k4 + q);      float p0 = __shfl(p, k4 + q);
            int s1 = __shfl(s, k4 + 4 + q);  float p1 = __shfl(p, k4 + 4 + q);
            int s2 = __shfl(s, k4 + 8 + q);  float p2 = __shfl(p, k4 + 8 + q);
            int s3 = __shfl(s, k4 + 12 + q); float p3 = __shfl(p, k4 + 12 + q);
            union { unsigned u; half_t h[2]; } u0, u1, u2, u3;
            u0.u = *(const unsigned*)&xh[(size_t)s0 * 32 + r15 * 2];
            u1.u = *(const unsigned*)&xh[(size_t)s1 * 32 + r15 * 2];
            u2.u = *(const unsigned*)&xh[(size_t)s2 * 32 + r15 * 2];
            u3.u = *(const unsigned*)&xh[(size_t)s3 * 32 + r15 * 2];
            a0 += p0 * (float)u0.h[0] + p1 * (float)u1.h[0] + p2 * (float)u2.h[0] + p3 * (float)u3.h[0];
            a1 += p0 * (float)u0.h[1] + p1 * (float)u1.h[1] + p2 * (float)u2.h[1] + p3 * (float)u3.h[1];
        }
        for (; k4 < cnt; k4 += 4) {
            int s0 = __shfl(s, k4 + q); float p0 = __shfl(p, k4 + q);
            union { unsigned u; half_t h[2]; } u0;
            u0.u = *(const unsigned*)&xh[(size_t)s0 * 32 + r15 * 2];
            a0 += p0 * (float)u0.h[0]; a1 += p0 * (float)u0.h[1];
        }
    }
#pragma unroll
    for (int o = 32; o; o >>= 1) pz += __shfl_xor(pz, o);
    a0 += __shfl_xor(a0, 16); a0 += __shfl_xor(a0, 32);
    a1 += __shfl_xor(a1, 16); a1 += __shfl_xor(a1, 32);
    if (q == 0) {
        float inv = 1.f / (pz + 1e-16f);
        union { unsigned u; half_t h[2]; } w;
        w.h[0] = (half_t)(a0 * inv); w.h[1] = (half_t)(a1 * inv);
        *(unsigned*)&P[(size_t)d * 32 + r15 * 2] = w.u;
    }
}

// ---------------- res-layer aggregation over Th (128ch): P[d] = sum alpha * Th[src] -----
__global__ __launch_bounds__(256) void agg_kernel(const half_t* __restrict__ F,
        const float* __restrict__ a_s, const float* __restrict__ a_dv,
        const int* __restrict__ csr_src, const int* __restrict__ off,
        half_t* __restrict__ P) {
    int d = (blockIdx.x * 256 + threadIdx.x) >> 6;
    int lane = threadIdx.x & 63;
    int q = lane >> 4, r15 = lane & 15;
    int beg = off[d], end = off[d + 1];
    float adv = a_dv[d];
    float pz = 0.f;
    float acc[8] = {0.f,0.f,0.f,0.f,0.f,0.f,0.f,0.f};
    for (int base = beg; base < end; base += 64) {
        int j = base + lane;
        int s = 0; float p = 0.f;
        if (j < end) {
            s = csr_src[j];
            float t = a_s[s] + adv;
            t = (t > 0.f) ? t : 0.2f * t;
            p = __expf(t);
        }
        pz += p;
        int cnt = end - base; if (cnt > 64) cnt = 64;
        int full = cnt & ~15;
        int k4 = 0;
        for (; k4 < full; k4 += 16) {
            int s0 = __shfl(s, k4 + q);      float p0 = __shfl(p, k4 + q);
            int s1 = __shfl(s, k4 + 4 + q);  float p1 = __shfl(p, k4 + 4 + q);
            int s2 = __shfl(s, k4 + 8 + q);  float p2 = __shfl(p, k4 + 8 + q);
            int s3 = __shfl(s, k4 + 12 + q); float p3 = __shfl(p, k4 + 12 + q);
            half8 h0 = *(const half8*)&F[(size_t)s0 * HIDD + r15 * 8];
            half8 h1 = *(const half8*)&F[(size_t)s1 * HIDD + r15 * 8];
            half8 h2 = *(const half8*)&F[(size_t)s2 * HIDD + r15 * 8];
            half8 h3 = *(const half8*)&F[(size_t)s3 * HIDD + r15 * 8];
#pragma unroll
            for (int i = 0; i < 8; ++i) acc[i] += p0 * (float)h0[i];
#pragma unroll
            for (int i = 0; i < 8; ++i) acc[i] += p1 * (float)h1[i];
#pragma unroll
            for (int i = 0; i < 8; ++i) acc[i] += p2 * (float)h2[i];
#pragma unroll
            for (int i = 0; i < 8; ++i) acc[i] += p3 * (float)h3[i];
        }
        for (; k4 < cnt; k4 += 4) {
            int s0 = __shfl(s, k4 + q); float p0 = __shfl(p, k4 + q);
            half8 h0 = *(const half8*)&F[(size_t)s0 * HIDD + r15 * 8];
#pragma unroll
            for (int i = 0; i < 8; ++i) acc[i] += p0 * (float)h0[i];
        }
    }
#pragma unroll
    for (int o = 32; o; o >>= 1) pz += __shfl_xor(pz, o);
#pragma unroll
    for (int i = 0; i < 8; ++i) {
        acc[i] += __shfl_xor(acc[i], 16);
        acc[i] += __shfl_xor(acc[i], 32);
    }
    if (q == 0) {
        float inv = 1.f / (pz + 1e-16f);
        union { int4 v; half_t hh[8]; } u;
#pragma unroll
        for (int i = 0; i < 8; ++i) u.hh[i] = (half_t)(acc[i] * inv);
        *(int4*)&P[(size_t)d * HIDD + r15 * 8] = u.v;
    }
}

// ---------------- GEMM + fused epilogue (bias, residual, LN, Th, next a_s/a_d) ---------
template <int K, bool RES>
__global__ __launch_bounds__(256) void gemm_kernel(const half_t* __restrict__ P,
        const half_t* __restrict__ Whl, const float* __restrict__ bias,
        float* __restrict__ Hbuf, half_t* __restrict__ Th,
        const float* __restrict__ gamma, const float* __restrict__ beta,
        const float* __restrict__ wsn, const float* __restrict__ wdn,
        float* __restrict__ a_s, float* __restrict__ a_d) {
    constexpr int KP = K + 8;
    __shared__ half_t Wt[128 * KP];
    __shared__ half_t OutT[64 * HIDD];
    int tid = threadIdx.x;
    int n0 = blockIdx.x * 64;
    for (int i = tid; i < 128 * (K / 8); i += 256) {
        int n = i / (K / 8), c = i % (K / 8);
        *(int4*)&Wt[n * KP + c * 8] = *(const int4*)&Whl[(size_t)n * K + c * 8];
    }
    int wv = tid >> 6, lane = tid & 63;
    int q = lane >> 4, r15 = lane & 15;
    half8 afrag[K / 32];
    int nodeA = n0 + wv * 16 + r15;
#pragma unroll
    for (int s = 0; s < K / 32; ++s)
        afrag[s] = *(const half8*)&P[(size_t)nodeA * K + s * 32 + q * 8];
    __syncthreads();
    f32x4 acc[8];
#pragma unroll
    for (int ct = 0; ct < 8; ++ct) {
        f32x4 c = {0.f, 0.f, 0.f, 0.f};
#pragma unroll
        for (int s = 0; s < K / 32; ++s) {
            half8 bfrag = *(const half8*)&Wt[(ct * 16 + r15) * KP + s * 32 + q * 8];
            c = __builtin_amdgcn_mfma_f32_16x16x32_f16(afrag[s], bfrag, c, 0, 0, 0);
        }
        acc[ct] = c;
    }
    int nodeD = n0 + wv * 16 + q * 4;   // + r
    float v[8][4];
#pragma unroll
    for (int ct = 0; ct < 8; ++ct) {
        int ch = ct * 16 + r15;
        float bv = bias[ch];
#pragma unroll
        for (int r = 0; r < 4; ++r) {
            float x2 = acc[ct][r] + bv;
            if (RES) x2 += Hbuf[(size_t)(nodeD + r) * HIDD + ch];
            else     x2 = fmaxf(x2, 0.f);
            v[ct][r] = x2;
            Hbuf[(size_t)(nodeD + r) * HIDD + ch] = x2;
        }
    }
    float sum[4] = {0.f,0.f,0.f,0.f};
#pragma unroll
    for (int ct = 0; ct < 8; ++ct)
#pragma unroll
        for (int r = 0; r < 4; ++r) sum[r] += v[ct][r];
#pragma unroll
    for (int o = 8; o; o >>= 1)
#pragma unroll
        for (int r = 0; r < 4; ++r) sum[r] += __shfl_xor(sum[r], o);
    float mu[4], var[4] = {0.f,0.f,0.f,0.f};
#pragma unroll
    for (int r = 0; r < 4; ++r) mu[r] = sum[r] * (1.f / HIDD);
#pragma unroll
    for (int ct = 0; ct < 8; ++ct)
#pragma unroll
        for (int r = 0; r < 4; ++r) { float dx = v[ct][r] - mu[r]; var[r] += dx * dx; }
#pragma unroll
    for (int o = 8; o; o >>= 1)
#pragma unroll
        for (int r = 0; r < 4; ++r) var[r] += __shfl_xor(var[r], o);
    float rs[4];
#pragma unroll
    for (int r = 0; r < 4; ++r) rs[r] = rsqrtf(var[r] * (1.f / HIDD) + 1e-5f);
    float asn[4] = {0.f,0.f,0.f,0.f}, adn[4] = {0.f,0.f,0.f,0.f};
#pragma unroll
    for (int ct = 0; ct < 8; ++ct) {
        int ch = ct * 16 + r15;
        float g = gamma[ch], be = beta[ch], wsv = wsn[ch], wdv = wdn[ch];
#pragma unroll
        for (int r = 0; r < 4; ++r) {
            float t = fmaxf((v[ct][r] - mu[r]) * rs[r] * g + be, 0.f);
            OutT[(wv * 16 + q * 4 + r) * HIDD + ch] = (half_t)t;
            asn[r] += t * wsv;
            adn[r] += t * wdv;
        }
    }
#pragma unroll
    for (int o = 8; o; o >>= 1)
#pragma unroll
        for (int r = 0; r < 4; ++r) { asn[r] += __shfl_xor(asn[r], o); adn[r] += __shfl_xor(adn[r], o); }
    if (r15 == 0) {
#pragma unroll
        for (int r = 0; r < 4; ++r) { a_s[nodeD + r] = asn[r]; a_d[nodeD + r] = adn[r]; }
    }
    __syncthreads();
    const int4* srcp = (const int4*)OutT;
    int4* dstp = (int4*)&Th[(size_t)n0 * HIDD];
    for (int i = tid; i < 64 * HIDD * 2 / 16; i += 256)
        dstp[i] = srcp[i];
}

// ---------------- last layer: GEMM + residual + LN + predictor head + softmax ----------
__global__ __launch_bounds__(256) void gemm_last_kernel(const half_t* __restrict__ P,
        const half_t* __restrict__ Whl, const float* __restrict__ bias,
        const float* __restrict__ Hbuf,
        const float* __restrict__ gamma, const float* __restrict__ beta,
        const half_t* __restrict__ W1h, const float* __restrict__ W2p,
        float* __restrict__ out) {
    __shared__ half_t Wt[128 * 136];
    __shared__ half_t OutT[64 * HIDD];
    int tid = threadIdx.x;
    int n0 = blockIdx.x * 64;
    for (int i = tid; i < 128 * 16; i += 256) {
        int n = i >> 4, c = i & 15;
        *(int4*)&Wt[n * 136 + c * 8] = *(const int4*)&Whl[(size_t)n * 128 + c * 8];
    }
    int wv = tid >> 6, lane = tid & 63;
    int q = lane >> 4, r15 = lane & 15;
    half8 afrag[4];
    int nodeA = n0 + wv * 16 + r15;
#pragma unroll
    for (int s = 0; s < 4; ++s)
        afrag[s] = *(const half8*)&P[(size_t)nodeA * HIDD + s * 32 + q * 8];
    __syncthreads();
    f32x4 acc[8];
#pragma unroll
    for (int ct = 0; ct < 8; ++ct) {
        f32x4 c = {0.f, 0.f, 0.f, 0.f};
#pragma unroll
        for (int s = 0; s < 4; ++s) {
            half8 bfrag = *(const half8*)&Wt[(ct * 16 + r15) * 136 + s * 32 + q * 8];
            c = __builtin_amdgcn_mfma_f32_16x16x32_f16(afrag[s], bfrag, c, 0, 0, 0);
        }
        acc[ct] = c;
    }
    int nodeD = n0 + wv * 16 + q * 4;
    float v[8][4];
#pragma unroll
    for (int ct = 0; ct < 8; ++ct) {
        int ch = ct * 16 + r15;
        float bv = bias[ch];
#pragma unroll
        for (int r = 0; r < 4; ++r)
            v[ct][r] = acc[ct][r] + bv + Hbuf[(size_t)(nodeD + r) * HIDD + ch];
    }
    float sum[4] = {0.f,0.f,0.f,0.f};
#pragma unroll
    for (int ct = 0; ct < 8; ++ct)
#pragma unroll
        for (int r = 0; r < 4; ++r) sum[r] += v[ct][r];
#pragma unroll
    for (int o = 8; o; o >>= 1)
#pragma unroll
        for (int r = 0; r < 4; ++r) sum[r] += __shfl_xor(sum[r], o);
    float mu[4], var[4] = {0.f,0.f,0.f,0.f};
#pragma unroll
    for (int r = 0; r < 4; ++r) mu[r] = sum[r] * (1.f / HIDD);
#pragma unroll
    for (int ct = 0; ct < 8; ++ct)
#pragma unroll
        for (int r = 0; r < 4; ++r) { float dx = v[ct][r] - mu[r]; var[r] += dx * dx; }
#pragma unroll
    for (int o = 8; o; o >>= 1)
#pragma unroll
        for (int r = 0; r < 4; ++r) var[r] += __shfl_xor(var[r], o);
    float rs[4];
#pragma unroll
    for (int r = 0; r < 4; ++r) rs[r] = rsqrtf(var[r] * (1.f / HIDD) + 1e-5f);
#pragma unroll
    for (int ct = 0; ct < 8; ++ct) {
        int ch = ct * 16 + r15;
        float g = gamma[ch], be = beta[ch];
#pragma unroll
        for (int r = 0; r < 4; ++r) {
            float t = fmaxf((v[ct][r] - mu[r]) * rs[r] * g + be, 0.f);
            OutT[(wv * 16 + q * 4 + r) * HIDD + ch] = (half_t)t;
        }
    }
    __syncthreads();
    // predictor head (nodes of this block all belong to head n0>>9)
    int head = n0 >> 9;
    const half_t* W1g = W1h + (size_t)head * 64 * 128;
    half8 pa[4];
#pragma unroll
    for (int s = 0; s < 4; ++s)
        pa[s] = *(const half8*)&OutT[(wv * 16 + r15) * HIDD + s * 32 + q * 8];
    float lg[3][4];
#pragma unroll
    for (int o = 0; o < 3; ++o)
#pragma unroll
        for (int r = 0; r < 4; ++r) lg[o][r] = 0.f;
#pragma unroll
    for (int ct2 = 0; ct2 < 4; ++ct2) {
        int n2 = ct2 * 16 + r15;
        f32x4 c = {0.f, 0.f, 0.f, 0.f};
#pragma unroll
        for (int s = 0; s < 4; ++s) {
            half8 bfrag = *(const half8*)&W1g[(size_t)n2 * 128 + s * 32 + q * 8];
            c = __builtin_amdgcn_mfma_f32_16x16x32_f16(pa[s], bfrag, c, 0, 0, 0);
        }
        float w2a = W2p[(size_t)head * 192 + n2 * 3 + 0];
        float w2b = W2p[(size_t)head * 192 + n2 * 3 + 1];
        float w2c = W2p[(size_t)head * 192 + n2 * 3 + 2];
#pragma unroll
        for (int r = 0; r < 4; ++r) {
            float t = fmaxf(c[r], 0.f);
            lg[0][r] += t * w2a;
            lg[1][r] += t * w2b;
            lg[2][r] += t * w2c;
        }
    }
#pragma unroll
    for (int o = 8; o; o >>= 1)
#pragma unroll
        for (int oo = 0; oo < 3; ++oo)
#pragma unroll
            for (int r = 0; r < 4; ++r) lg[oo][r] += __shfl_xor(lg[oo][r], o);
    if (r15 == 0) {
#pragma unroll
        for (int r = 0; r < 4; ++r) {
            int node = nodeD + r;
            float l0 = lg[0][r], l1 = lg[1][r], l2 = lg[2][r];
            float mx = fmaxf(l0, fmaxf(l1, l2));
            float e0 = __expf(l0 - mx), e1 = __expf(l1 - mx), e2 = __expf(l2 - mx);
            float inv = 1.f / (e0 + e1 + e2);
            float* op = out + (size_t)node * OUTC;
            op[0] = e0 * inv; op[1] = e1 * inv; op[2] = e2 * inv;
        }
    }
}

extern "C" void kernel_launch(void* const* d_in, const int* in_sizes, int n_in,
                              void* d_out, int out_size, void* d_ws, size_t ws_size,
                              hipStream_t stream) {
    const float* x        = (const float*)d_in[0];
    const int*   ei       = (const int*)d_in[1];
    const float* W0       = (const float*)d_in[2];
    const float* att_src0 = (const float*)d_in[3];
    const float* att_dst0 = (const float*)d_in[4];
    const float* bias0    = (const float*)d_in[5];
    const float* W_res    = (const float*)d_in[6];
    const float* as_res   = (const float*)d_in[7];
    const float* ad_res   = (const float*)d_in[8];
    const float* b_res    = (const float*)d_in[9];
    const float* gamma    = (const float*)d_in[10];
    const float* beta     = (const float*)d_in[11];
    const float* W1p      = (const float*)d_in[12];
    const float* W2p      = (const float*)d_in[13];
    float* out = (float*)d_out;

    int E = in_sizes[1] / 2;
    int Etot = E + NND;

    char* p = (char*)d_ws;
    auto alloc = [&](size_t bytes) { void* r = (void*)p; p += (bytes + 255) & ~(size_t)255; return r; };
    int*    counts  = (int*)alloc((size_t)NND * 4);
    int*    off     = (int*)alloc((size_t)(NND + 1) * 4);
    int*    rank    = (int*)alloc((size_t)Etot * 4);
    int*    csr_src = (int*)alloc((size_t)Etot * 4);
    half_t* xh      = (half_t*)alloc((size_t)NND * 32 * 2);
    half_t* Pbuf    = (half_t*)alloc((size_t)NND * HIDD * 2);
    half_t* Th      = (half_t*)alloc((size_t)NND * HIDD * 2);
    float*  Hbuf    = (float*)alloc((size_t)NND * HIDD * 4);
    float*  a_s     = (float*)alloc((size_t)NND * 4);
    float*  a_d     = (float*)alloc((size_t)NND * 4);
    half_t* Wh      = (half_t*)alloc((size_t)4 * HIDD * HIDD * 2);
    half_t* W1h     = (half_t*)alloc((size_t)NHEAD * 64 * HIDD * 2);
    half_t* W0t     = (half_t*)alloc((size_t)HIDD * 32 * 2);
    float*  wvec    = (float*)alloc((size_t)1280 * 4);

    int egrid = (Etot + 255) / 256;

    prep_kernel<<<1122, 256, 0, stream>>>(W0, W_res, W1p, att_src0, att_dst0,
                                          as_res, ad_res, x, Wh, W1h, W0t, wvec, xh, counts);
    a0_kernel<<<512, 256, 0, stream>>>(xh, wvec, a_s, a_d);
    count_kernel<<<egrid, 256, 0, stream>>>(ei, E, counts, rank);
    scan_kernel<<<1, 1024, 0, stream>>>(counts, off);
    fill_kernel<<<egrid, 256, 0, stream>>>(ei, E, off, rank, csr_src);

    // layer 0: P0 = softmax-agg(xh); h = relu(P0@W0 + b0); Th = relu(LN0(h)); a_s/a_d for block 0
    agg0_kernel<<<NND / 4, 256, 0, stream>>>(xh, a_s, a_d, csr_src, off, Pbuf);
    gemm_kernel<32, false><<<NND / 64, 256, 0, stream>>>(Pbuf, W0t, bias0, Hbuf, Th,
        gamma, beta, wvec + 128, wvec + 640 + 128, a_s, a_d);

    // res blocks 0..2: P = agg(Th); h += P@W + b; Th = relu(LN(h)); next a_s/a_d
    for (int i = 0; i < 3; ++i) {
        agg_kernel<<<NND / 4, 256, 0, stream>>>(Th, a_s, a_d, csr_src, off, Pbuf);
        gemm_kernel<128, true><<<NND / 64, 256, 0, stream>>>(Pbuf, Wh + (size_t)i * 16384,
            b_res + i * HIDD, Hbuf, Th,
            gamma + (i + 1) * HIDD, beta + (i + 1) * HIDD,
            wvec + (i + 2) * 128, wvec + 640 + (i + 2) * 128, a_s, a_d);
    }

    // res block 3 + final LN(gamma0) + predictor heads + softmax, fully fused
    agg_kernel<<<NND / 4, 256, 0, stream>>>(Th, a_s, a_d, csr_src, off, Pbuf);
    gemm_last_kernel<<<NND / 64, 256, 0, stream>>>(Pbuf, Wh + (size_t)3 * 16384,
        b_res + 3 * HIDD, Hbuf, gamma, beta, W1h, W2p, out);
}

// Round 6
// 293.368 us; speedup vs baseline: 2.4814x; 1.0312x over previous
//
#include <hip/hip_runtime.h>
#include <math.h>

#define NND   32768
#define HIDD  128
#define NHEAD 64
#define BSS   512
#define OUTC  3

typedef _Float16 half_t;
typedef __attribute__((ext_vector_type(8))) _Float16 half8;  // MFMA A/B frag
typedef __attribute__((ext_vector_type(4))) float f32x4;     // MFMA C/D frag

// ---------------- prep: weight transposes, w_s/w_d GEMVs, x cast, edge count ----------
__global__ __launch_bounds__(256) void prep_kernel(const float* __restrict__ W0,
        const float* __restrict__ W_res, const float* __restrict__ W1p,
        const float* __restrict__ as0, const float* __restrict__ ad0,
        const float* __restrict__ as_res, const float* __restrict__ ad_res,
        const float* __restrict__ x, const int* __restrict__ ei, int E,
        half_t* __restrict__ Wh, half_t* __restrict__ W1h, half_t* __restrict__ W0t,
        float* __restrict__ wvec, half_t* __restrict__ xh,
        int* __restrict__ counts, int* __restrict__ rank) {
    int b = blockIdx.x, tid = threadIdx.x;
    if (b < 64) {            // W_res[l][128k][128n] -> Wh[l][n][k] fp16
        __shared__ float tile[32][33];
        int l = b >> 4, t = b & 15;
        int k0 = (t >> 2) * 32, n0 = (t & 3) * 32;
        const float* src = W_res + (size_t)l * 128 * 128;
        half_t* dst = Wh + (size_t)l * 128 * 128;
        int c = tid & 31, r0 = tid >> 5;
#pragma unroll
        for (int i = 0; i < 4; ++i) tile[r0 + i * 8][c] = src[(size_t)(k0 + r0 + i * 8) * 128 + n0 + c];
        __syncthreads();
#pragma unroll
        for (int i = 0; i < 4; ++i) dst[(size_t)(n0 + r0 + i * 8) * 128 + k0 + c] = (half_t)tile[c][r0 + i * 8];
    } else if (b < 576) {    // W1p[h][128k][64n] -> W1h[h][n][k] fp16
        __shared__ float tile[32][33];
        int bb = b - 64, head = bb >> 3, t = bb & 7;
        int k0 = (t >> 1) * 32, n0 = (t & 1) * 32;
        const float* src = W1p + (size_t)head * 128 * 64;
        half_t* dst = W1h + (size_t)head * 64 * 128;
        int c = tid & 31, r0 = tid >> 5;
#pragma unroll
        for (int i = 0; i < 4; ++i) tile[r0 + i * 8][c] = src[(size_t)(k0 + r0 + i * 8) * 64 + n0 + c];
        __syncthreads();
#pragma unroll
        for (int i = 0; i < 4; ++i) dst[(size_t)(n0 + r0 + i * 8) * 128 + k0 + c] = (half_t)tile[c][r0 + i * 8];
    } else if (b == 576) {   // W0[32k][128n] -> W0t[n][k] fp16
        __shared__ float t0[32][129];
        for (int i = tid; i < 4096; i += 256) t0[i >> 7][i & 127] = W0[i];
        __syncthreads();
        for (int i = tid; i < 4096; i += 256) { int n = i >> 5, k = i & 31; W0t[n * 32 + k] = (half_t)t0[k][n]; }
    } else if (b == 577) {   // w_s[l][k] = sum_n W_l[k][n]*att_src_l[n]; w_d at wvec+640
        for (int task = tid; task < 1088; task += 256) {
            const float* row; const float* att; int slot, sd;
            if (task < 64) {
                int k = task >> 1; sd = task & 1;
                row = W0 + k * 128; att = sd ? ad0 : as0; slot = k;
            } else {
                int tt = task - 64; int l = 1 + tt / 256; int r = tt % 256;
                int k = r >> 1; sd = r & 1;
                row = W_res + (size_t)(l - 1) * 16384 + k * 128;
                att = (sd ? ad_res : as_res) + (l - 1) * 128;
                slot = l * 128 + k;
            }
            float s = 0.f;
            for (int n = 0; n < 128; ++n) s += row[n] * att[n];
            (sd ? wvec + 640 : wvec)[slot] = s;
        }
    } else if (b < 1090) {   // x fp32 -> xh fp16
        int b2 = b - 578;
        const float* xs = x + (size_t)b2 * 64 * 32;
        half_t* xd = xh + (size_t)b2 * 64 * 32;
        for (int i = tid; i < 1024; i += 256) {
            float2 v = ((const float2*)xs)[i];
            union { unsigned u; half_t h[2]; } cv;
            cv.h[0] = (half_t)v.x; cv.h[1] = (half_t)v.y;
            ((unsigned*)xd)[i] = cv.u;
        }
    } else {                 // edge count + rank (counts pre-zeroed by memset)
        int j = (b - 1090) * 256 + tid;
        int Etot = E + NND;
        if (j >= Etot) return;
        int dst = (j < E) ? ei[E + j] : (j - E);
        rank[j] = atomicAdd(&counts[dst], 1);
    }
}

__global__ __launch_bounds__(1024) void scan_kernel(const int* __restrict__ counts,
                                                    int* __restrict__ off) {
    __shared__ int sums[1024];
    int tid = threadIdx.x;
    int base = tid * 32;
    int tmp[32];
    int run = 0;
#pragma unroll
    for (int i = 0; i < 8; ++i) {
        int4 c4 = *(const int4*)&counts[base + i * 4];
        tmp[i*4+0] = run; run += c4.x;
        tmp[i*4+1] = run; run += c4.y;
        tmp[i*4+2] = run; run += c4.z;
        tmp[i*4+3] = run; run += c4.w;
    }
    sums[tid] = run;
    __syncthreads();
    for (int d = 1; d < 1024; d <<= 1) {
        int v = (tid >= d) ? sums[tid - d] : 0;
        __syncthreads();
        sums[tid] += v;
        __syncthreads();
    }
    int ebase = (tid == 0) ? 0 : sums[tid - 1];
#pragma unroll
    for (int i = 0; i < 32; ++i) off[base + i] = ebase + tmp[i];
    if (tid == 1023) off[NND] = sums[1023];
}

// ---------------- CSR fill + layer-0 attention scalars (merged) ----------------
__global__ __launch_bounds__(256) void fill_a0_kernel(const int* __restrict__ ei, int E, int egrid,
        const int* __restrict__ off, const int* __restrict__ rank, int* __restrict__ csr_src,
        const half_t* __restrict__ xh, const float* __restrict__ wvec,
        float* __restrict__ a_s, float* __restrict__ a_d) {
    int b = blockIdx.x, tid = threadIdx.x;
    if (b < egrid) {
        int j = b * 256 + tid;
        int Etot = E + NND;
        if (j >= Etot) return;
        int src, dst;
        if (j < E) { src = ei[j]; dst = ei[E + j]; }
        else       { src = j - E; dst = j - E; }
        csr_src[off[dst] + rank[j]] = src;
    } else {
        __shared__ float ws0[32], wd0[32];
        if (tid < 32) { ws0[tid] = wvec[tid]; wd0[tid] = wvec[640 + tid]; }
        __syncthreads();
        int g = (b - egrid) * 256 + tid;
        int node = g >> 2, part = g & 3;
        half8 xv = *(const half8*)&xh[(size_t)node * 32 + part * 8];
        float s = 0.f, d2 = 0.f;
#pragma unroll
        for (int j = 0; j < 8; ++j) { float f = (float)xv[j]; s += f * ws0[part * 8 + j]; d2 += f * wd0[part * 8 + j]; }
        s += __shfl_xor(s, 1); s += __shfl_xor(s, 2);
        d2 += __shfl_xor(d2, 1); d2 += __shfl_xor(d2, 2);
        if (part == 0) { a_s[node] = s; a_d[node] = d2; }
    }
}

// ---------------- layer-0 aggregation over xh (32ch) ----------------
__global__ __launch_bounds__(256) void agg0_kernel(const half_t* __restrict__ xh,
        const float* __restrict__ a_s, const float* __restrict__ a_dv,
        const int* __restrict__ csr_src, const int* __restrict__ off,
        half_t* __restrict__ P) {
    int d = (blockIdx.x * 256 + threadIdx.x) >> 6;
    int lane = threadIdx.x & 63;
    int q = lane >> 4, r15 = lane & 15;
    int beg = off[d], end = off[d + 1];
    float adv = a_dv[d];
    float pz = 0.f, a0 = 0.f, a1 = 0.f;
    for (int base = beg; base < end; base += 64) {
        int j = base + lane;
        int s = 0; float p = 0.f;
        if (j < end) {
            s = csr_src[j];
            float t = a_s[s] + adv;
            t = (t > 0.f) ? t : 0.2f * t;
            p = __expf(t);
        }
        pz += p;
        int cnt = end - base; if (cnt > 64) cnt = 64;
        int full = cnt & ~15;
        int k4 = 0;
        for (; k4 < full; k4 += 16) {
            int s0 = __shfl(s, k4 + q);      float p0 = __shfl(p, k4 + q);
            int s1 = __shfl(s, k4 + 4 + q);  float p1 = __shfl(p, k4 + 4 + q);
            int s2 = __shfl(s, k4 + 8 + q);  float p2 = __shfl(p, k4 + 8 + q);
            int s3 = __shfl(s, k4 + 12 + q); float p3 = __shfl(p, k4 + 12 + q);
            union { unsigned u; half_t h[2]; } u0, u1, u2, u3;
            u0.u = *(const unsigned*)&xh[(size_t)s0 * 32 + r15 * 2];
            u1.u = *(const unsigned*)&xh[(size_t)s1 * 32 + r15 * 2];
            u2.u = *(const unsigned*)&xh[(size_t)s2 * 32 + r15 * 2];
            u3.u = *(const unsigned*)&xh[(size_t)s3 * 32 + r15 * 2];
            a0 += p0 * (float)u0.h[0] + p1 * (float)u1.h[0] + p2 * (float)u2.h[0] + p3 * (float)u3.h[0];
            a1 += p0 * (float)u0.h[1] + p1 * (float)u1.h[1] + p2 * (float)u2.h[1] + p3 * (float)u3.h[1];
        }
        for (; k4 < cnt; k4 += 4) {
            int s0 = __shfl(s, k4 + q); float p0 = __shfl(p, k4 + q);
            union { unsigned u; half_t h[2]; } u0;
            u0.u = *(const unsigned*)&xh[(size_t)s0 * 32 + r15 * 2];
            a0 += p0 * (float)u0.h[0]; a1 += p0 * (float)u0.h[1];
        }
    }
#pragma unroll
    for (int o = 32; o; o >>= 1) pz += __shfl_xor(pz, o);
    a0 += __shfl_xor(a0, 16); a0 += __shfl_xor(a0, 32);
    a1 += __shfl_xor(a1, 16); a1 += __shfl_xor(a1, 32);
    if (q == 0) {
        float inv = 1.f / (pz + 1e-16f);
        union { unsigned u; half_t h[2]; } w;
        w.h[0] = (half_t)(a0 * inv); w.h[1] = (half_t)(a1 * inv);
        *(unsigned*)&P[(size_t)d * 32 + r15 * 2] = w.u;
    }
}

// ---------------- res-layer aggregation over Th (128ch) ----------------
__global__ __launch_bounds__(256) void agg_kernel(const half_t* __restrict__ F,
        const float* __restrict__ a_s, const float* __restrict__ a_dv,
        const int* __restrict__ csr_src, const int* __restrict__ off,
        half_t* __restrict__ P) {
    int d = (blockIdx.x * 256 + threadIdx.x) >> 6;
    int lane = threadIdx.x & 63;
    int q = lane >> 4, r15 = lane & 15;
    int beg = off[d], end = off[d + 1];
    float adv = a_dv[d];
    float pz = 0.f;
    float acc[8] = {0.f,0.f,0.f,0.f,0.f,0.f,0.f,0.f};
    for (int base = beg; base < end; base += 64) {
        int j = base + lane;
        int s = 0; float p = 0.f;
        if (j < end) {
            s = csr_src[j];
            float t = a_s[s] + adv;
            t = (t > 0.f) ? t : 0.2f * t;
            p = __expf(t);
        }
        pz += p;
        int cnt = end - base; if (cnt > 64) cnt = 64;
        int full = cnt & ~15;
        int k4 = 0;
        for (; k4 < full; k4 += 16) {
            int s0 = __shfl(s, k4 + q);      float p0 = __shfl(p, k4 + q);
            int s1 = __shfl(s, k4 + 4 + q);  float p1 = __shfl(p, k4 + 4 + q);
            int s2 = __shfl(s, k4 + 8 + q);  float p2 = __shfl(p, k4 + 8 + q);
            int s3 = __shfl(s, k4 + 12 + q); float p3 = __shfl(p, k4 + 12 + q);
            half8 h0 = *(const half8*)&F[(size_t)s0 * HIDD + r15 * 8];
            half8 h1 = *(const half8*)&F[(size_t)s1 * HIDD + r15 * 8];
            half8 h2 = *(const half8*)&F[(size_t)s2 * HIDD + r15 * 8];
            half8 h3 = *(const half8*)&F[(size_t)s3 * HIDD + r15 * 8];
#pragma unroll
            for (int i = 0; i < 8; ++i) acc[i] += p0 * (float)h0[i];
#pragma unroll
            for (int i = 0; i < 8; ++i) acc[i] += p1 * (float)h1[i];
#pragma unroll
            for (int i = 0; i < 8; ++i) acc[i] += p2 * (float)h2[i];
#pragma unroll
            for (int i = 0; i < 8; ++i) acc[i] += p3 * (float)h3[i];
        }
        for (; k4 < cnt; k4 += 4) {
            int s0 = __shfl(s, k4 + q); float p0 = __shfl(p, k4 + q);
            half8 h0 = *(const half8*)&F[(size_t)s0 * HIDD + r15 * 8];
#pragma unroll
            for (int i = 0; i < 8; ++i) acc[i] += p0 * (float)h0[i];
        }
    }
#pragma unroll
    for (int o = 32; o; o >>= 1) pz += __shfl_xor(pz, o);
#pragma unroll
    for (int i = 0; i < 8; ++i) {
        acc[i] += __shfl_xor(acc[i], 16);
        acc[i] += __shfl_xor(acc[i], 32);
    }
    if (q == 0) {
        float inv = 1.f / (pz + 1e-16f);
        union { int4 v; half_t hh[8]; } u;
#pragma unroll
        for (int i = 0; i < 8; ++i) u.hh[i] = (half_t)(acc[i] * inv);
        *(int4*)&P[(size_t)d * HIDD + r15 * 8] = u.v;
    }
}

// ---------------- GEMM + coalesced fused epilogue (bias, residual fp16, LN, Th, next a_s/a_d) ----
// LDS: Wt region overlaid with a 64x132-float redistribution tile (union via char buffer)
template <int K, bool RES>
__global__ __launch_bounds__(256) void gemm_kernel(const half_t* __restrict__ P,
        const half_t* __restrict__ Whl, const float* __restrict__ bias,
        half_t* __restrict__ Hh, half_t* __restrict__ Th,
        const float* __restrict__ gamma, const float* __restrict__ beta,
        const float* __restrict__ wsn, const float* __restrict__ wdn,
        float* __restrict__ a_s, float* __restrict__ a_d) {
    constexpr int KP = K + 8;
    constexpr int WB = 128 * KP * 2;
    constexpr int VB = 64 * 132 * 4;
    __shared__ __align__(16) char smraw[(WB > VB) ? WB : VB];
    half_t* w = (half_t*)smraw;
    float* vv = (float*)smraw;
    int tid = threadIdx.x;
    int n0 = blockIdx.x * 64;
    for (int i = tid; i < 128 * (K / 8); i += 256) {
        int n = i / (K / 8), c = i % (K / 8);
        *(int4*)&w[n * KP + c * 8] = *(const int4*)&Whl[(size_t)n * K + c * 8];
    }
    int wv = tid >> 6, lane = tid & 63;
    int q = lane >> 4, r15 = lane & 15;
    half8 afrag[K / 32];
    int nodeA = n0 + wv * 16 + r15;
#pragma unroll
    for (int s = 0; s < K / 32; ++s)
        afrag[s] = *(const half8*)&P[(size_t)nodeA * K + s * 32 + q * 8];
    __syncthreads();
    f32x4 acc[8];
#pragma unroll
    for (int ct = 0; ct < 8; ++ct) {
        f32x4 c = {0.f, 0.f, 0.f, 0.f};
#pragma unroll
        for (int s = 0; s < K / 32; ++s) {
            half8 bfrag = *(const half8*)&w[(ct * 16 + r15) * KP + s * 32 + q * 8];
            c = __builtin_amdgcn_mfma_f32_16x16x32_f16(afrag[s], bfrag, c, 0, 0, 0);
        }
        acc[ct] = c;
    }
    __syncthreads();   // done with w
    // redistribute: vv[node_local][ch]
#pragma unroll
    for (int ct = 0; ct < 8; ++ct)
#pragma unroll
        for (int r = 0; r < 4; ++r)
            vv[(wv * 16 + q * 4 + r) * 132 + ct * 16 + r15] = acc[ct][r];
    __syncthreads();
    // phase 2: group of 16 lanes per node, 8 ch per lane, 4 passes
    int grp = tid >> 4, sub = tid & 15;
    float4 bi0 = *(const float4*)&bias[sub * 8],  bi1 = *(const float4*)&bias[sub * 8 + 4];
    float4 g0  = *(const float4*)&gamma[sub * 8], g1  = *(const float4*)&gamma[sub * 8 + 4];
    float4 be0 = *(const float4*)&beta[sub * 8],  be1 = *(const float4*)&beta[sub * 8 + 4];
    float4 ws0 = *(const float4*)&wsn[sub * 8],   ws1 = *(const float4*)&wsn[sub * 8 + 4];
    float4 wd0 = *(const float4*)&wdn[sub * 8],   wd1 = *(const float4*)&wdn[sub * 8 + 4];
    float bi[8] = {bi0.x,bi0.y,bi0.z,bi0.w,bi1.x,bi1.y,bi1.z,bi1.w};
    float gg[8] = {g0.x,g0.y,g0.z,g0.w,g1.x,g1.y,g1.z,g1.w};
    float be[8] = {be0.x,be0.y,be0.z,be0.w,be1.x,be1.y,be1.z,be1.w};
    float ws[8] = {ws0.x,ws0.y,ws0.z,ws0.w,ws1.x,ws1.y,ws1.z,ws1.w};
    float wd[8] = {wd0.x,wd0.y,wd0.z,wd0.w,wd1.x,wd1.y,wd1.z,wd1.w};
#pragma unroll
    for (int pp = 0; pp < 4; ++pp) {
        int nl = grp + pp * 16;
        int node = n0 + nl;
        float v8[8];
#pragma unroll
        for (int j = 0; j < 8; ++j) v8[j] = vv[nl * 132 + sub * 8 + j] + bi[j];
        if (RES) {
            half8 hold = *(const half8*)&Hh[(size_t)node * HIDD + sub * 8];
#pragma unroll
            for (int j = 0; j < 8; ++j) v8[j] += (float)hold[j];
        } else {
#pragma unroll
            for (int j = 0; j < 8; ++j) v8[j] = fmaxf(v8[j], 0.f);
        }
        // write residual state (fp16)
        union { int4 i4; half_t h[8]; } hw;
#pragma unroll
        for (int j = 0; j < 8; ++j) hw.h[j] = (half_t)v8[j];
        *(int4*)&Hh[(size_t)node * HIDD + sub * 8] = hw.i4;
        // LN over the 16-lane group
        float sum = 0.f;
#pragma unroll
        for (int j = 0; j < 8; ++j) sum += v8[j];
#pragma unroll
        for (int o = 8; o; o >>= 1) sum += __shfl_xor(sum, o);
        float mu = sum * (1.f / HIDD);
        float var = 0.f;
#pragma unroll
        for (int j = 0; j < 8; ++j) { float dx = v8[j] - mu; var += dx * dx; }
#pragma unroll
        for (int o = 8; o; o >>= 1) var += __shfl_xor(var, o);
        float rs = rsqrtf(var * (1.f / HIDD) + 1e-5f);
        union { int4 i4; half_t h[8]; } tw;
        float asn = 0.f, adn = 0.f;
#pragma unroll
        for (int j = 0; j < 8; ++j) {
            float t = fmaxf((v8[j] - mu) * rs * gg[j] + be[j], 0.f);
            tw.h[j] = (half_t)t;
            asn += t * ws[j];
            adn += t * wd[j];
        }
        *(int4*)&Th[(size_t)node * HIDD + sub * 8] = tw.i4;
#pragma unroll
        for (int o = 8; o; o >>= 1) { asn += __shfl_xor(asn, o); adn += __shfl_xor(adn, o); }
        if (sub == 0) { a_s[node] = asn; a_d[node] = adn; }
    }
}

// ---------------- last layer: GEMM + residual + LN + predictor head + softmax ----------
__global__ __launch_bounds__(256) void gemm_last_kernel(const half_t* __restrict__ P,
        const half_t* __restrict__ Whl, const float* __restrict__ bias,
        const half_t* __restrict__ Hh,
        const float* __restrict__ gamma, const float* __restrict__ beta,
        const half_t* __restrict__ W1h, const float* __restrict__ W2p,
        float* __restrict__ out) {
    __shared__ __align__(16) char smraw[128 * 136 * 2];
    half_t* w = (half_t*)smraw;
    float* vv = (float*)smraw;
    int tid = threadIdx.x;
    int n0 = blockIdx.x * 64;
    for (int i = tid; i < 128 * 16; i += 256) {
        int n = i >> 4, c = i & 15;
        *(int4*)&w[n * 136 + c * 8] = *(const int4*)&Whl[(size_t)n * 128 + c * 8];
    }
    int wv = tid >> 6, lane = tid & 63;
    int q = lane >> 4, r15 = lane & 15;
    half8 afrag[4];
    int nodeA = n0 + wv * 16 + r15;
#pragma unroll
    for (int s = 0; s < 4; ++s)
        afrag[s] = *(const half8*)&P[(size_t)nodeA * HIDD + s * 32 + q * 8];
    __syncthreads();
    f32x4 acc[8];
#pragma unroll
    for (int ct = 0; ct < 8; ++ct) {
        f32x4 c = {0.f, 0.f, 0.f, 0.f};
#pragma unroll
        for (int s = 0; s < 4; ++s) {
            half8 bfrag = *(const half8*)&w[(ct * 16 + r15) * 136 + s * 32 + q * 8];
            c = __builtin_amdgcn_mfma_f32_16x16x32_f16(afrag[s], bfrag, c, 0, 0, 0);
        }
        acc[ct] = c;
    }
    __syncthreads();
#pragma unroll
    for (int ct = 0; ct < 8; ++ct)
#pragma unroll
        for (int r = 0; r < 4; ++r)
            vv[(wv * 16 + q * 4 + r) * 132 + ct * 16 + r15] = acc[ct][r];
    __syncthreads();
    int grp = tid >> 4, sub = tid & 15;
    float4 bi0 = *(const float4*)&bias[sub * 8],  bi1 = *(const float4*)&bias[sub * 8 + 4];
    float4 g0  = *(const float4*)&gamma[sub * 8], g1  = *(const float4*)&gamma[sub * 8 + 4];
    float4 be0 = *(const float4*)&beta[sub * 8],  be1 = *(const float4*)&beta[sub * 8 + 4];
    float bi[8] = {bi0.x,bi0.y,bi0.z,bi0.w,bi1.x,bi1.y,bi1.z,bi1.w};
    float gg[8] = {g0.x,g0.y,g0.z,g0.w,g1.x,g1.y,g1.z,g1.w};
    float be[8] = {be0.x,be0.y,be0.z,be0.w,be1.x,be1.y,be1.z,be1.w};
    half_t tv[4][8];
#pragma unroll
    for (int pp = 0; pp < 4; ++pp) {
        int nl = grp + pp * 16;
        int node = n0 + nl;
        float v8[8];
        half8 hold = *(const half8*)&Hh[(size_t)node * HIDD + sub * 8];
#pragma unroll
        for (int j = 0; j < 8; ++j) v8[j] = vv[nl * 132 + sub * 8 + j] + bi[j] + (float)hold[j];
        float sum = 0.f;
#pragma unroll
        for (int j = 0; j < 8; ++j) sum += v8[j];
#pragma unroll
        for (int o = 8; o; o >>= 1) sum += __shfl_xor(sum, o);
        float mu = sum * (1.f / HIDD);
        float var = 0.f;
#pragma unroll
        for (int j = 0; j < 8; ++j) { float dx = v8[j] - mu; var += dx * dx; }
#pragma unroll
        for (int o = 8; o; o >>= 1) var += __shfl_xor(var, o);
        float rs = rsqrtf(var * (1.f / HIDD) + 1e-5f);
#pragma unroll
        for (int j = 0; j < 8; ++j)
            tv[pp][j] = (half_t)fmaxf((v8[j] - mu) * rs * gg[j] + be[j], 0.f);
    }
    __syncthreads();   // done reading vv; rewrite w region with T tile (136-pad half rows)
#pragma unroll
    for (int pp = 0; pp < 4; ++pp) {
        int nl = grp + pp * 16;
        union { int4 i4; half_t h[8]; } u;
#pragma unroll
        for (int j = 0; j < 8; ++j) u.h[j] = tv[pp][j];
        *(int4*)&w[nl * 136 + sub * 8] = u.i4;
    }
    __syncthreads();
    // predictor head (nodes of this block all belong to head n0>>9)
    int head = n0 >> 9;
    const half_t* W1g = W1h + (size_t)head * 64 * 128;
    half8 pa[4];
#pragma unroll
    for (int s = 0; s < 4; ++s)
        pa[s] = *(const half8*)&w[(wv * 16 + r15) * 136 + s * 32 + q * 8];
    float lg[3][4];
#pragma unroll
    for (int o = 0; o < 3; ++o)
#pragma unroll
        for (int r = 0; r < 4; ++r) lg[o][r] = 0.f;
#pragma unroll
    for (int ct2 = 0; ct2 < 4; ++ct2) {
        int n2 = ct2 * 16 + r15;
        f32x4 c = {0.f, 0.f, 0.f, 0.f};
#pragma unroll
        for (int s = 0; s < 4; ++s) {
            half8 bfrag = *(const half8*)&W1g[(size_t)n2 * 128 + s * 32 + q * 8];
            c = __builtin_amdgcn_mfma_f32_16x16x32_f16(pa[s], bfrag, c, 0, 0, 0);
        }
        float w2a = W2p[(size_t)head * 192 + n2 * 3 + 0];
        float w2b = W2p[(size_t)head * 192 + n2 * 3 + 1];
        float w2c = W2p[(size_t)head * 192 + n2 * 3 + 2];
#pragma unroll
        for (int r = 0; r < 4; ++r) {
            float t = fmaxf(c[r], 0.f);
            lg[0][r] += t * w2a;
            lg[1][r] += t * w2b;
            lg[2][r] += t * w2c;
        }
    }
#pragma unroll
    for (int o = 8; o; o >>= 1)
#pragma unroll
        for (int oo = 0; oo < 3; ++oo)
#pragma unroll
            for (int r = 0; r < 4; ++r) lg[oo][r] += __shfl_xor(lg[oo][r], o);
    if (r15 == 0) {
        int nodeD = n0 + wv * 16 + q * 4;
#pragma unroll
        for (int r = 0; r < 4; ++r) {
            float l0 = lg[0][r], l1 = lg[1][r], l2 = lg[2][r];
            float mx = fmaxf(l0, fmaxf(l1, l2));
            float e0 = __expf(l0 - mx), e1 = __expf(l1 - mx), e2 = __expf(l2 - mx);
            float inv = 1.f / (e0 + e1 + e2);
            float* op = out + (size_t)(nodeD + r) * OUTC;
            op[0] = e0 * inv; op[1] = e1 * inv; op[2] = e2 * inv;
        }
    }
}

extern "C" void kernel_launch(void* const* d_in, const int* in_sizes, int n_in,
                              void* d_out, int out_size, void* d_ws, size_t ws_size,
                              hipStream_t stream) {
    const float* x        = (const float*)d_in[0];
    const int*   ei       = (const int*)d_in[1];
    const float* W0       = (const float*)d_in[2];
    const float* att_src0 = (const float*)d_in[3];
    const float* att_dst0 = (const float*)d_in[4];
    const float* bias0    = (const float*)d_in[5];
    const float* W_res    = (const float*)d_in[6];
    const float* as_res   = (const float*)d_in[7];
    const float* ad_res   = (const float*)d_in[8];
    const float* b_res    = (const float*)d_in[9];
    const float* gamma    = (const float*)d_in[10];
    const float* beta     = (const float*)d_in[11];
    const float* W1p      = (const float*)d_in[12];
    const float* W2p      = (const float*)d_in[13];
    float* out = (float*)d_out;

    int E = in_sizes[1] / 2;
    int Etot = E + NND;

    char* p = (char*)d_ws;
    auto alloc = [&](size_t bytes) { void* r = (void*)p; p += (bytes + 255) & ~(size_t)255; return r; };
    int*    counts  = (int*)alloc((size_t)NND * 4);
    int*    off     = (int*)alloc((size_t)(NND + 1) * 4);
    int*    rank    = (int*)alloc((size_t)Etot * 4);
    int*    csr_src = (int*)alloc((size_t)Etot * 4);
    half_t* xh      = (half_t*)alloc((size_t)NND * 32 * 2);
    half_t* Pbuf    = (half_t*)alloc((size_t)NND * HIDD * 2);
    half_t* Th      = (half_t*)alloc((size_t)NND * HIDD * 2);
    half_t* Hh      = (half_t*)alloc((size_t)NND * HIDD * 2);
    float*  a_s     = (float*)alloc((size_t)NND * 4);
    float*  a_d     = (float*)alloc((size_t)NND * 4);
    half_t* Wh      = (half_t*)alloc((size_t)4 * HIDD * HIDD * 2);
    half_t* W1h     = (half_t*)alloc((size_t)NHEAD * 64 * HIDD * 2);
    half_t* W0t     = (half_t*)alloc((size_t)HIDD * 32 * 2);
    float*  wvec    = (float*)alloc((size_t)1280 * 4);

    int egrid = (Etot + 255) / 256;

    hipMemsetAsync(counts, 0, (size_t)NND * 4, stream);
    prep_kernel<<<1090 + egrid, 256, 0, stream>>>(W0, W_res, W1p, att_src0, att_dst0,
        as_res, ad_res, x, ei, E, Wh, W1h, W0t, wvec, xh, counts, rank);
    scan_kernel<<<1, 1024, 0, stream>>>(counts, off);
    fill_a0_kernel<<<egrid + 512, 256, 0, stream>>>(ei, E, egrid, off, rank, csr_src,
                                                    xh, wvec, a_s, a_d);

    // layer 0
    agg0_kernel<<<NND / 4, 256, 0, stream>>>(xh, a_s, a_d, csr_src, off, Pbuf);
    gemm_kernel<32, false><<<NND / 64, 256, 0, stream>>>(Pbuf, W0t, bias0, Hh, Th,
        gamma, beta, wvec + 128, wvec + 640 + 128, a_s, a_d);

    // res blocks 0..2
    for (int i = 0; i < 3; ++i) {
        agg_kernel<<<NND / 4, 256, 0, stream>>>(Th, a_s, a_d, csr_src, off, Pbuf);
        gemm_kernel<128, true><<<NND / 64, 256, 0, stream>>>(Pbuf, Wh + (size_t)i * 16384,
            b_res + i * HIDD, Hh, Th,
            gamma + (i + 1) * HIDD, beta + (i + 1) * HIDD,
            wvec + (i + 2) * 128, wvec + 640 + (i + 2) * 128, a_s, a_d);
    }

    // res block 3 + final LN + predictor + softmax
    agg_kernel<<<NND / 4, 256, 0, stream>>>(Th, a_s, a_d, csr_src, off, Pbuf);
    gemm_last_kernel<<<NND / 64, 256, 0, stream>>>(Pbuf, Wh + (size_t)3 * 16384,
        b_res + 3 * HIDD, Hh, gamma, beta, W1h, W2p, out);
}

// Round 7
// 281.145 us; speedup vs baseline: 2.5893x; 1.0435x over previous
//
#include <hip/hip_runtime.h>
#include <hip/hip_fp8.h>
#include <math.h>

#define NND   32768
#define HIDD  128
#define NHEAD 64
#define BSS   512
#define OUTC  3

typedef _Float16 half_t;
typedef __attribute__((ext_vector_type(8))) _Float16 half8;  // MFMA A/B frag
typedef __attribute__((ext_vector_type(4))) float f32x4;     // MFMA C/D frag

__device__ __forceinline__ unsigned enc_fp8x4(float a, float b, float c, float d) {
    __hip_fp8x4_e4m3 q(make_float4(a, b, c, d));
    return (unsigned)q.__x;
}
__device__ __forceinline__ float4 dec_fp8x4(unsigned v) {
    __hip_fp8x4_e4m3 t; t.__x = (__hip_fp8x4_storage_t)v;
    return (float4)t;
}

// ---------------- prep: weight transposes, w_s/w_d GEMVs, x cast, edge count ----------
__global__ __launch_bounds__(256) void prep_kernel(const float* __restrict__ W0,
        const float* __restrict__ W_res, const float* __restrict__ W1p,
        const float* __restrict__ as0, const float* __restrict__ ad0,
        const float* __restrict__ as_res, const float* __restrict__ ad_res,
        const float* __restrict__ x, const int* __restrict__ ei, int E,
        half_t* __restrict__ Wh, half_t* __restrict__ W1h, half_t* __restrict__ W0t,
        float* __restrict__ wvec, half_t* __restrict__ xh,
        int* __restrict__ counts, int* __restrict__ rank) {
    int b = blockIdx.x, tid = threadIdx.x;
    if (b < 64) {            // W_res[l][128k][128n] -> Wh[l][n][k] fp16
        __shared__ float tile[32][33];
        int l = b >> 4, t = b & 15;
        int k0 = (t >> 2) * 32, n0 = (t & 3) * 32;
        const float* src = W_res + (size_t)l * 128 * 128;
        half_t* dst = Wh + (size_t)l * 128 * 128;
        int c = tid & 31, r0 = tid >> 5;
#pragma unroll
        for (int i = 0; i < 4; ++i) tile[r0 + i * 8][c] = src[(size_t)(k0 + r0 + i * 8) * 128 + n0 + c];
        __syncthreads();
#pragma unroll
        for (int i = 0; i < 4; ++i) dst[(size_t)(n0 + r0 + i * 8) * 128 + k0 + c] = (half_t)tile[c][r0 + i * 8];
    } else if (b < 576) {    // W1p[h][128k][64n] -> W1h[h][n][k] fp16
        __shared__ float tile[32][33];
        int bb = b - 64, head = bb >> 3, t = bb & 7;
        int k0 = (t >> 1) * 32, n0 = (t & 1) * 32;
        const float* src = W1p + (size_t)head * 128 * 64;
        half_t* dst = W1h + (size_t)head * 64 * 128;
        int c = tid & 31, r0 = tid >> 5;
#pragma unroll
        for (int i = 0; i < 4; ++i) tile[r0 + i * 8][c] = src[(size_t)(k0 + r0 + i * 8) * 64 + n0 + c];
        __syncthreads();
#pragma unroll
        for (int i = 0; i < 4; ++i) dst[(size_t)(n0 + r0 + i * 8) * 128 + k0 + c] = (half_t)tile[c][r0 + i * 8];
    } else if (b == 576) {   // W0[32k][128n] -> W0t[n][k] fp16
        __shared__ float t0[32][129];
        for (int i = tid; i < 4096; i += 256) t0[i >> 7][i & 127] = W0[i];
        __syncthreads();
        for (int i = tid; i < 4096; i += 256) { int n = i >> 5, k = i & 31; W0t[n * 32 + k] = (half_t)t0[k][n]; }
    } else if (b == 577) {   // w_s[l][k] = sum_n W_l[k][n]*att_src_l[n]; w_d at wvec+640
        for (int task = tid; task < 1088; task += 256) {
            const float* row; const float* att; int slot, sd;
            if (task < 64) {
                int k = task >> 1; sd = task & 1;
                row = W0 + k * 128; att = sd ? ad0 : as0; slot = k;
            } else {
                int tt = task - 64; int l = 1 + tt / 256; int r = tt % 256;
                int k = r >> 1; sd = r & 1;
                row = W_res + (size_t)(l - 1) * 16384 + k * 128;
                att = (sd ? ad_res : as_res) + (l - 1) * 128;
                slot = l * 128 + k;
            }
            float s = 0.f;
            for (int n = 0; n < 128; ++n) s += row[n] * att[n];
            (sd ? wvec + 640 : wvec)[slot] = s;
        }
    } else if (b < 1090) {   // x fp32 -> xh fp16
        int b2 = b - 578;
        const float* xs = x + (size_t)b2 * 64 * 32;
        half_t* xd = xh + (size_t)b2 * 64 * 32;
        for (int i = tid; i < 1024; i += 256) {
            float2 v = ((const float2*)xs)[i];
            union { unsigned u; half_t h[2]; } cv;
            cv.h[0] = (half_t)v.x; cv.h[1] = (half_t)v.y;
            ((unsigned*)xd)[i] = cv.u;
        }
    } else {                 // edge count + rank (counts pre-zeroed by memset)
        int j = (b - 1090) * 256 + tid;
        int Etot = E + NND;
        if (j >= Etot) return;
        int dst = (j < E) ? ei[E + j] : (j - E);
        rank[j] = atomicAdd(&counts[dst], 1);
    }
}

__global__ __launch_bounds__(1024) void scan_kernel(const int* __restrict__ counts,
                                                    int* __restrict__ off) {
    __shared__ int sums[1024];
    int tid = threadIdx.x;
    int base = tid * 32;
    int tmp[32];
    int run = 0;
#pragma unroll
    for (int i = 0; i < 8; ++i) {
        int4 c4 = *(const int4*)&counts[base + i * 4];
        tmp[i*4+0] = run; run += c4.x;
        tmp[i*4+1] = run; run += c4.y;
        tmp[i*4+2] = run; run += c4.z;
        tmp[i*4+3] = run; run += c4.w;
    }
    sums[tid] = run;
    __syncthreads();
    for (int d = 1; d < 1024; d <<= 1) {
        int v = (tid >= d) ? sums[tid - d] : 0;
        __syncthreads();
        sums[tid] += v;
        __syncthreads();
    }
    int ebase = (tid == 0) ? 0 : sums[tid - 1];
#pragma unroll
    for (int i = 0; i < 32; ++i) off[base + i] = ebase + tmp[i];
    if (tid == 1023) off[NND] = sums[1023];
}

// ---------------- CSR fill + layer-0 attention scalars (merged) ----------------
__global__ __launch_bounds__(256) void fill_a0_kernel(const int* __restrict__ ei, int E, int egrid,
        const int* __restrict__ off, const int* __restrict__ rank, int* __restrict__ csr_src,
        const half_t* __restrict__ xh, const float* __restrict__ wvec,
        float* __restrict__ a_s, float* __restrict__ a_d) {
    int b = blockIdx.x, tid = threadIdx.x;
    if (b < egrid) {
        int j = b * 256 + tid;
        int Etot = E + NND;
        if (j >= Etot) return;
        int src, dst;
        if (j < E) { src = ei[j]; dst = ei[E + j]; }
        else       { src = j - E; dst = j - E; }
        csr_src[off[dst] + rank[j]] = src;
    } else {
        __shared__ float ws0[32], wd0[32];
        if (tid < 32) { ws0[tid] = wvec[tid]; wd0[tid] = wvec[640 + tid]; }
        __syncthreads();
        int g = (b - egrid) * 256 + tid;
        int node = g >> 2, part = g & 3;
        half8 xv = *(const half8*)&xh[(size_t)node * 32 + part * 8];
        float s = 0.f, d2 = 0.f;
#pragma unroll
        for (int j = 0; j < 8; ++j) { float f = (float)xv[j]; s += f * ws0[part * 8 + j]; d2 += f * wd0[part * 8 + j]; }
        s += __shfl_xor(s, 1); s += __shfl_xor(s, 2);
        d2 += __shfl_xor(d2, 1); d2 += __shfl_xor(d2, 2);
        if (part == 0) { a_s[node] = s; a_d[node] = d2; }
    }
}

// ---------------- layer-0 aggregation over xh (32ch, fp16) ----------------
__global__ __launch_bounds__(256) void agg0_kernel(const half_t* __restrict__ xh,
        const float* __restrict__ a_s, const float* __restrict__ a_dv,
        const int* __restrict__ csr_src, const int* __restrict__ off,
        half_t* __restrict__ P) {
    int d = (blockIdx.x * 256 + threadIdx.x) >> 6;
    int lane = threadIdx.x & 63;
    int q = lane >> 4, r15 = lane & 15;
    int beg = off[d], end = off[d + 1];
    float adv = a_dv[d];
    float pz = 0.f, a0 = 0.f, a1 = 0.f;
    for (int base = beg; base < end; base += 64) {
        int j = base + lane;
        int s = 0; float p = 0.f;
        if (j < end) {
            s = csr_src[j];
            float t = a_s[s] + adv;
            t = (t > 0.f) ? t : 0.2f * t;
            p = __expf(t);
        }
        pz += p;
        int cnt = end - base; if (cnt > 64) cnt = 64;
        int full = cnt & ~15;
        int k4 = 0;
        for (; k4 < full; k4 += 16) {
            int s0 = __shfl(s, k4 + q);      float p0 = __shfl(p, k4 + q);
            int s1 = __shfl(s, k4 + 4 + q);  float p1 = __shfl(p, k4 + 4 + q);
            int s2 = __shfl(s, k4 + 8 + q);  float p2 = __shfl(p, k4 + 8 + q);
            int s3 = __shfl(s, k4 + 12 + q); float p3 = __shfl(p, k4 + 12 + q);
            union { unsigned u; half_t h[2]; } u0, u1, u2, u3;
            u0.u = *(const unsigned*)&xh[(size_t)s0 * 32 + r15 * 2];
            u1.u = *(const unsigned*)&xh[(size_t)s1 * 32 + r15 * 2];
            u2.u = *(const unsigned*)&xh[(size_t)s2 * 32 + r15 * 2];
            u3.u = *(const unsigned*)&xh[(size_t)s3 * 32 + r15 * 2];
            a0 += p0 * (float)u0.h[0] + p1 * (float)u1.h[0] + p2 * (float)u2.h[0] + p3 * (float)u3.h[0];
            a1 += p0 * (float)u0.h[1] + p1 * (float)u1.h[1] + p2 * (float)u2.h[1] + p3 * (float)u3.h[1];
        }
        for (; k4 < cnt; k4 += 4) {
            int s0 = __shfl(s, k4 + q); float p0 = __shfl(p, k4 + q);
            union { unsigned u; half_t h[2]; } u0;
            u0.u = *(const unsigned*)&xh[(size_t)s0 * 32 + r15 * 2];
            a0 += p0 * (float)u0.h[0]; a1 += p0 * (float)u0.h[1];
        }
    }
#pragma unroll
    for (int o = 32; o; o >>= 1) pz += __shfl_xor(pz, o);
    a0 += __shfl_xor(a0, 16); a0 += __shfl_xor(a0, 32);
    a1 += __shfl_xor(a1, 16); a1 += __shfl_xor(a1, 32);
    if (q == 0) {
        float inv = 1.f / (pz + 1e-16f);
        union { unsigned u; half_t h[2]; } w;
        w.h[0] = (half_t)(a0 * inv); w.h[1] = (half_t)(a1 * inv);
        *(unsigned*)&P[(size_t)d * 32 + r15 * 2] = w.u;
    }
}

// ---------------- res-layer aggregation over Th8 (128ch, fp8 e4m3, L2-resident) -------
__global__ __launch_bounds__(256) void agg_kernel(const unsigned char* __restrict__ F8,
        const float* __restrict__ a_s, const float* __restrict__ a_dv,
        const int* __restrict__ csr_src, const int* __restrict__ off,
        half_t* __restrict__ P) {
    int d = (blockIdx.x * 256 + threadIdx.x) >> 6;
    int lane = threadIdx.x & 63;
    int q = lane >> 4, r15 = lane & 15;
    int beg = off[d], end = off[d + 1];
    float adv = a_dv[d];
    float pz = 0.f;
    float acc[8] = {0.f,0.f,0.f,0.f,0.f,0.f,0.f,0.f};
    for (int base = beg; base < end; base += 64) {
        int j = base + lane;
        int s = 0; float p = 0.f;
        if (j < end) {
            s = csr_src[j];
            float t = a_s[s] + adv;
            t = (t > 0.f) ? t : 0.2f * t;
            p = __expf(t);
        }
        pz += p;
        int cnt = end - base; if (cnt > 64) cnt = 64;
        int full = cnt & ~15;
        int k4 = 0;
        for (; k4 < full; k4 += 16) {
            int s0 = __shfl(s, k4 + q);      float p0 = __shfl(p, k4 + q);
            int s1 = __shfl(s, k4 + 4 + q);  float p1 = __shfl(p, k4 + 4 + q);
            int s2 = __shfl(s, k4 + 8 + q);  float p2 = __shfl(p, k4 + 8 + q);
            int s3 = __shfl(s, k4 + 12 + q); float p3 = __shfl(p, k4 + 12 + q);
            uint2 r0 = *(const uint2*)&F8[(size_t)s0 * HIDD + r15 * 8];
            uint2 r1 = *(const uint2*)&F8[(size_t)s1 * HIDD + r15 * 8];
            uint2 r2 = *(const uint2*)&F8[(size_t)s2 * HIDD + r15 * 8];
            uint2 r3 = *(const uint2*)&F8[(size_t)s3 * HIDD + r15 * 8];
            float4 f;
            f = dec_fp8x4(r0.x); acc[0]+=p0*f.x; acc[1]+=p0*f.y; acc[2]+=p0*f.z; acc[3]+=p0*f.w;
            f = dec_fp8x4(r0.y); acc[4]+=p0*f.x; acc[5]+=p0*f.y; acc[6]+=p0*f.z; acc[7]+=p0*f.w;
            f = dec_fp8x4(r1.x); acc[0]+=p1*f.x; acc[1]+=p1*f.y; acc[2]+=p1*f.z; acc[3]+=p1*f.w;
            f = dec_fp8x4(r1.y); acc[4]+=p1*f.x; acc[5]+=p1*f.y; acc[6]+=p1*f.z; acc[7]+=p1*f.w;
            f = dec_fp8x4(r2.x); acc[0]+=p2*f.x; acc[1]+=p2*f.y; acc[2]+=p2*f.z; acc[3]+=p2*f.w;
            f = dec_fp8x4(r2.y); acc[4]+=p2*f.x; acc[5]+=p2*f.y; acc[6]+=p2*f.z; acc[7]+=p2*f.w;
            f = dec_fp8x4(r3.x); acc[0]+=p3*f.x; acc[1]+=p3*f.y; acc[2]+=p3*f.z; acc[3]+=p3*f.w;
            f = dec_fp8x4(r3.y); acc[4]+=p3*f.x; acc[5]+=p3*f.y; acc[6]+=p3*f.z; acc[7]+=p3*f.w;
        }
        for (; k4 < cnt; k4 += 4) {
            int s0 = __shfl(s, k4 + q); float p0 = __shfl(p, k4 + q);
            uint2 r0 = *(const uint2*)&F8[(size_t)s0 * HIDD + r15 * 8];
            float4 f;
            f = dec_fp8x4(r0.x); acc[0]+=p0*f.x; acc[1]+=p0*f.y; acc[2]+=p0*f.z; acc[3]+=p0*f.w;
            f = dec_fp8x4(r0.y); acc[4]+=p0*f.x; acc[5]+=p0*f.y; acc[6]+=p0*f.z; acc[7]+=p0*f.w;
        }
    }
#pragma unroll
    for (int o = 32; o; o >>= 1) pz += __shfl_xor(pz, o);
#pragma unroll
    for (int i = 0; i < 8; ++i) {
        acc[i] += __shfl_xor(acc[i], 16);
        acc[i] += __shfl_xor(acc[i], 32);
    }
    if (q == 0) {
        float inv = 1.f / (pz + 1e-16f);
        union { int4 v; half_t hh[8]; } u;
#pragma unroll
        for (int i = 0; i < 8; ++i) u.hh[i] = (half_t)(acc[i] * inv);
        *(int4*)&P[(size_t)d * HIDD + r15 * 8] = u.v;
    }
}

// ---------------- GEMM + coalesced fused epilogue (bias, residual fp16, LN, Th8, a_s/a_d) ----
template <int K, bool RES>
__global__ __launch_bounds__(256) void gemm_kernel(const half_t* __restrict__ P,
        const half_t* __restrict__ Whl, const float* __restrict__ bias,
        half_t* __restrict__ Hh, unsigned char* __restrict__ Th8,
        const float* __restrict__ gamma, const float* __restrict__ beta,
        const float* __restrict__ wsn, const float* __restrict__ wdn,
        float* __restrict__ a_s, float* __restrict__ a_d) {
    constexpr int KP = K + 8;
    constexpr int WB = 128 * KP * 2;
    constexpr int VB = 64 * 132 * 4;
    __shared__ __align__(16) char smraw[(WB > VB) ? WB : VB];
    half_t* w = (half_t*)smraw;
    float* vv = (float*)smraw;
    int tid = threadIdx.x;
    int n0 = blockIdx.x * 64;
    for (int i = tid; i < 128 * (K / 8); i += 256) {
        int n = i / (K / 8), c = i % (K / 8);
        *(int4*)&w[n * KP + c * 8] = *(const int4*)&Whl[(size_t)n * K + c * 8];
    }
    int wv = tid >> 6, lane = tid & 63;
    int q = lane >> 4, r15 = lane & 15;
    half8 afrag[K / 32];
    int nodeA = n0 + wv * 16 + r15;
#pragma unroll
    for (int s = 0; s < K / 32; ++s)
        afrag[s] = *(const half8*)&P[(size_t)nodeA * K + s * 32 + q * 8];
    __syncthreads();
    f32x4 acc[8];
#pragma unroll
    for (int ct = 0; ct < 8; ++ct) {
        f32x4 c = {0.f, 0.f, 0.f, 0.f};
#pragma unroll
        for (int s = 0; s < K / 32; ++s) {
            half8 bfrag = *(const half8*)&w[(ct * 16 + r15) * KP + s * 32 + q * 8];
            c = __builtin_amdgcn_mfma_f32_16x16x32_f16(afrag[s], bfrag, c, 0, 0, 0);
        }
        acc[ct] = c;
    }
    __syncthreads();   // done with w
#pragma unroll
    for (int ct = 0; ct < 8; ++ct)
#pragma unroll
        for (int r = 0; r < 4; ++r)
            vv[(wv * 16 + q * 4 + r) * 132 + ct * 16 + r15] = acc[ct][r];
    __syncthreads();
    // phase 2: group of 16 lanes per node, 8 ch per lane, 4 passes
    int grp = tid >> 4, sub = tid & 15;
    float4 bi0 = *(const float4*)&bias[sub * 8],  bi1 = *(const float4*)&bias[sub * 8 + 4];
    float4 g0  = *(const float4*)&gamma[sub * 8], g1  = *(const float4*)&gamma[sub * 8 + 4];
    float4 be0 = *(const float4*)&beta[sub * 8],  be1 = *(const float4*)&beta[sub * 8 + 4];
    float4 ws0 = *(const float4*)&wsn[sub * 8],   ws1 = *(const float4*)&wsn[sub * 8 + 4];
    float4 wd0 = *(const float4*)&wdn[sub * 8],   wd1 = *(const float4*)&wdn[sub * 8 + 4];
    float bi[8] = {bi0.x,bi0.y,bi0.z,bi0.w,bi1.x,bi1.y,bi1.z,bi1.w};
    float gg[8] = {g0.x,g0.y,g0.z,g0.w,g1.x,g1.y,g1.z,g1.w};
    float be[8] = {be0.x,be0.y,be0.z,be0.w,be1.x,be1.y,be1.z,be1.w};
    float ws[8] = {ws0.x,ws0.y,ws0.z,ws0.w,ws1.x,ws1.y,ws1.z,ws1.w};
    float wd[8] = {wd0.x,wd0.y,wd0.z,wd0.w,wd1.x,wd1.y,wd1.z,wd1.w};
#pragma unroll
    for (int pp = 0; pp < 4; ++pp) {
        int nl = grp + pp * 16;
        int node = n0 + nl;
        float v8[8];
#pragma unroll
        for (int j = 0; j < 8; ++j) v8[j] = vv[nl * 132 + sub * 8 + j] + bi[j];
        if (RES) {
            half8 hold = *(const half8*)&Hh[(size_t)node * HIDD + sub * 8];
#pragma unroll
            for (int j = 0; j < 8; ++j) v8[j] += (float)hold[j];
        } else {
#pragma unroll
            for (int j = 0; j < 8; ++j) v8[j] = fmaxf(v8[j], 0.f);
        }
        union { int4 i4; half_t h[8]; } hw;
#pragma unroll
        for (int j = 0; j < 8; ++j) hw.h[j] = (half_t)v8[j];
        *(int4*)&Hh[(size_t)node * HIDD + sub * 8] = hw.i4;
        // LN over the 16-lane group
        float sum = 0.f;
#pragma unroll
        for (int j = 0; j < 8; ++j) sum += v8[j];
#pragma unroll
        for (int o = 8; o; o >>= 1) sum += __shfl_xor(sum, o);
        float mu = sum * (1.f / HIDD);
        float var = 0.f;
#pragma unroll
        for (int j = 0; j < 8; ++j) { float dx = v8[j] - mu; var += dx * dx; }
#pragma unroll
        for (int o = 8; o; o >>= 1) var += __shfl_xor(var, o);
        float rs = rsqrtf(var * (1.f / HIDD) + 1e-5f);
        float tt[8];
        float asn = 0.f, adn = 0.f;
#pragma unroll
        for (int j = 0; j < 8; ++j) {
            float t = fmaxf((v8[j] - mu) * rs * gg[j] + be[j], 0.f);
            tt[j] = t;
            asn += t * ws[j];
            adn += t * wd[j];
        }
        uint2 tw;
        tw.x = enc_fp8x4(tt[0], tt[1], tt[2], tt[3]);
        tw.y = enc_fp8x4(tt[4], tt[5], tt[6], tt[7]);
        *(uint2*)&Th8[(size_t)node * HIDD + sub * 8] = tw;
#pragma unroll
        for (int o = 8; o; o >>= 1) { asn += __shfl_xor(asn, o); adn += __shfl_xor(adn, o); }
        if (sub == 0) { a_s[node] = asn; a_d[node] = adn; }
    }
}

// ---------------- last layer: GEMM + residual + LN + predictor head + softmax ----------
__global__ __launch_bounds__(256) void gemm_last_kernel(const half_t* __restrict__ P,
        const half_t* __restrict__ Whl, const float* __restrict__ bias,
        const half_t* __restrict__ Hh,
        const float* __restrict__ gamma, const float* __restrict__ beta,
        const half_t* __restrict__ W1h, const float* __restrict__ W2p,
        float* __restrict__ out) {
    __shared__ __align__(16) char smraw[128 * 136 * 2];
    half_t* w = (half_t*)smraw;
    float* vv = (float*)smraw;
    int tid = threadIdx.x;
    int n0 = blockIdx.x * 64;
    for (int i = tid; i < 128 * 16; i += 256) {
        int n = i >> 4, c = i & 15;
        *(int4*)&w[n * 136 + c * 8] = *(const int4*)&Whl[(size_t)n * 128 + c * 8];
    }
    int wv = tid >> 6, lane = tid & 63;
    int q = lane >> 4, r15 = lane & 15;
    half8 afrag[4];
    int nodeA = n0 + wv * 16 + r15;
#pragma unroll
    for (int s = 0; s < 4; ++s)
        afrag[s] = *(const half8*)&P[(size_t)nodeA * HIDD + s * 32 + q * 8];
    __syncthreads();
    f32x4 acc[8];
#pragma unroll
    for (int ct = 0; ct < 8; ++ct) {
        f32x4 c = {0.f, 0.f, 0.f, 0.f};
#pragma unroll
        for (int s = 0; s < 4; ++s) {
            half8 bfrag = *(const half8*)&w[(ct * 16 + r15) * 136 + s * 32 + q * 8];
            c = __builtin_amdgcn_mfma_f32_16x16x32_f16(afrag[s], bfrag, c, 0, 0, 0);
        }
        acc[ct] = c;
    }
    __syncthreads();
#pragma unroll
    for (int ct = 0; ct < 8; ++ct)
#pragma unroll
        for (int r = 0; r < 4; ++r)
            vv[(wv * 16 + q * 4 + r) * 132 + ct * 16 + r15] = acc[ct][r];
    __syncthreads();
    int grp = tid >> 4, sub = tid & 15;
    float4 bi0 = *(const float4*)&bias[sub * 8],  bi1 = *(const float4*)&bias[sub * 8 + 4];
    float4 g0  = *(const float4*)&gamma[sub * 8], g1  = *(const float4*)&gamma[sub * 8 + 4];
    float4 be0 = *(const float4*)&beta[sub * 8],  be1 = *(const float4*)&beta[sub * 8 + 4];
    float bi[8] = {bi0.x,bi0.y,bi0.z,bi0.w,bi1.x,bi1.y,bi1.z,bi1.w};
    float gg[8] = {g0.x,g0.y,g0.z,g0.w,g1.x,g1.y,g1.z,g1.w};
    float be[8] = {be0.x,be0.y,be0.z,be0.w,be1.x,be1.y,be1.z,be1.w};
    half_t tv[4][8];
#pragma unroll
    for (int pp = 0; pp < 4; ++pp) {
        int nl = grp + pp * 16;
        int node = n0 + nl;
        float v8[8];
        half8 hold = *(const half8*)&Hh[(size_t)node * HIDD + sub * 8];
#pragma unroll
        for (int j = 0; j < 8; ++j) v8[j] = vv[nl * 132 + sub * 8 + j] + bi[j] + (float)hold[j];
        float sum = 0.f;
#pragma unroll
        for (int j = 0; j < 8; ++j) sum += v8[j];
#pragma unroll
        for (int o = 8; o; o >>= 1) sum += __shfl_xor(sum, o);
        float mu = sum * (1.f / HIDD);
        float var = 0.f;
#pragma unroll
        for (int j = 0; j < 8; ++j) { float dx = v8[j] - mu; var += dx * dx; }
#pragma unroll
        for (int o = 8; o; o >>= 1) var += __shfl_xor(var, o);
        float rs = rsqrtf(var * (1.f / HIDD) + 1e-5f);
#pragma unroll
        for (int j = 0; j < 8; ++j)
            tv[pp][j] = (half_t)fmaxf((v8[j] - mu) * rs * gg[j] + be[j], 0.f);
    }
    __syncthreads();   // done reading vv; rewrite w region with T tile (136-pad half rows)
#pragma unroll
    for (int pp = 0; pp < 4; ++pp) {
        int nl = grp + pp * 16;
        union { int4 i4; half_t h[8]; } u;
#pragma unroll
        for (int j = 0; j < 8; ++j) u.h[j] = tv[pp][j];
        *(int4*)&w[nl * 136 + sub * 8] = u.i4;
    }
    __syncthreads();
    // predictor head (nodes of this block all belong to head n0>>9)
    int head = n0 >> 9;
    const half_t* W1g = W1h + (size_t)head * 64 * 128;
    half8 pa[4];
#pragma unroll
    for (int s = 0; s < 4; ++s)
        pa[s] = *(const half8*)&w[(wv * 16 + r15) * 136 + s * 32 + q * 8];
    float lg[3][4];
#pragma unroll
    for (int o = 0; o < 3; ++o)
#pragma unroll
        for (int r = 0; r < 4; ++r) lg[o][r] = 0.f;
#pragma unroll
    for (int ct2 = 0; ct2 < 4; ++ct2) {
        int n2 = ct2 * 16 + r15;
        f32x4 c = {0.f, 0.f, 0.f, 0.f};
#pragma unroll
        for (int s = 0; s < 4; ++s) {
            half8 bfrag = *(const half8*)&W1g[(size_t)n2 * 128 + s * 32 + q * 8];
            c = __builtin_amdgcn_mfma_f32_16x16x32_f16(pa[s], bfrag, c, 0, 0, 0);
        }
        float w2a = W2p[(size_t)head * 192 + n2 * 3 + 0];
        float w2b = W2p[(size_t)head * 192 + n2 * 3 + 1];
        float w2c = W2p[(size_t)head * 192 + n2 * 3 + 2];
#pragma unroll
        for (int r = 0; r < 4; ++r) {
            float t = fmaxf(c[r], 0.f);
            lg[0][r] += t * w2a;
            lg[1][r] += t * w2b;
            lg[2][r] += t * w2c;
        }
    }
#pragma unroll
    for (int o = 8; o; o >>= 1)
#pragma unroll
        for (int oo = 0; oo < 3; ++oo)
#pragma unroll
            for (int r = 0; r < 4; ++r) lg[oo][r] += __shfl_xor(lg[oo][r], o);
    if (r15 == 0) {
        int nodeD = n0 + wv * 16 + q * 4;
#pragma unroll
        for (int r = 0; r < 4; ++r) {
            float l0 = lg[0][r], l1 = lg[1][r], l2 = lg[2][r];
            float mx = fmaxf(l0, fmaxf(l1, l2));
            float e0 = __expf(l0 - mx), e1 = __expf(l1 - mx), e2 = __expf(l2 - mx);
            float inv = 1.f / (e0 + e1 + e2);
            float* op = out + (size_t)(nodeD + r) * OUTC;
            op[0] = e0 * inv; op[1] = e1 * inv; op[2] = e2 * inv;
        }
    }
}

extern "C" void kernel_launch(void* const* d_in, const int* in_sizes, int n_in,
                              void* d_out, int out_size, void* d_ws, size_t ws_size,
                              hipStream_t stream) {
    const float* x        = (const float*)d_in[0];
    const int*   ei       = (const int*)d_in[1];
    const float* W0       = (const float*)d_in[2];
    const float* att_src0 = (const float*)d_in[3];
    const float* att_dst0 = (const float*)d_in[4];
    const float* bias0    = (const float*)d_in[5];
    const float* W_res    = (const float*)d_in[6];
    const float* as_res   = (const float*)d_in[7];
    const float* ad_res   = (const float*)d_in[8];
    const float* b_res    = (const float*)d_in[9];
    const float* gamma    = (const float*)d_in[10];
    const float* beta     = (const float*)d_in[11];
    const float* W1p      = (const float*)d_in[12];
    const float* W2p      = (const float*)d_in[13];
    float* out = (float*)d_out;

    int E = in_sizes[1] / 2;
    int Etot = E + NND;

    char* p = (char*)d_ws;
    auto alloc = [&](size_t bytes) { void* r = (void*)p; p += (bytes + 255) & ~(size_t)255; return r; };
    int*    counts  = (int*)alloc((size_t)NND * 4);
    int*    off     = (int*)alloc((size_t)(NND + 1) * 4);
    int*    rank    = (int*)alloc((size_t)Etot * 4);
    int*    csr_src = (int*)alloc((size_t)Etot * 4);
    half_t* xh      = (half_t*)alloc((size_t)NND * 32 * 2);
    half_t* Pbuf    = (half_t*)alloc((size_t)NND * HIDD * 2);
    unsigned char* Th8 = (unsigned char*)alloc((size_t)NND * HIDD);
    half_t* Hh      = (half_t*)alloc((size_t)NND * HIDD * 2);
    float*  a_s     = (float*)alloc((size_t)NND * 4);
    float*  a_d     = (float*)alloc((size_t)NND * 4);
    half_t* Wh      = (half_t*)alloc((size_t)4 * HIDD * HIDD * 2);
    half_t* W1h     = (half_t*)alloc((size_t)NHEAD * 64 * HIDD * 2);
    half_t* W0t     = (half_t*)alloc((size_t)HIDD * 32 * 2);
    float*  wvec    = (float*)alloc((size_t)1280 * 4);

    int egrid = (Etot + 255) / 256;

    hipMemsetAsync(counts, 0, (size_t)NND * 4, stream);
    prep_kernel<<<1090 + egrid, 256, 0, stream>>>(W0, W_res, W1p, att_src0, att_dst0,
        as_res, ad_res, x, ei, E, Wh, W1h, W0t, wvec, xh, counts, rank);
    scan_kernel<<<1, 1024, 0, stream>>>(counts, off);
    fill_a0_kernel<<<egrid + 512, 256, 0, stream>>>(ei, E, egrid, off, rank, csr_src,
                                                    xh, wvec, a_s, a_d);

    // layer 0
    agg0_kernel<<<NND / 4, 256, 0, stream>>>(xh, a_s, a_d, csr_src, off, Pbuf);
    gemm_kernel<32, false><<<NND / 64, 256, 0, stream>>>(Pbuf, W0t, bias0, Hh, Th8,
        gamma, beta, wvec + 128, wvec + 640 + 128, a_s, a_d);

    // res blocks 0..2
    for (int i = 0; i < 3; ++i) {
        agg_kernel<<<NND / 4, 256, 0, stream>>>(Th8, a_s, a_d, csr_src, off, Pbuf);
        gemm_kernel<128, true><<<NND / 64, 256, 0, stream>>>(Pbuf, Wh + (size_t)i * 16384,
            b_res + i * HIDD, Hh, Th8,
            gamma + (i + 1) * HIDD, beta + (i + 1) * HIDD,
            wvec + (i + 2) * 128, wvec + 640 + (i + 2) * 128, a_s, a_d);
    }

    // res block 3 + final LN + predictor + softmax
    agg_kernel<<<NND / 4, 256, 0, stream>>>(Th8, a_s, a_d, csr_src, off, Pbuf);
    gemm_last_kernel<<<NND / 64, 256, 0, stream>>>(Pbuf, Wh + (size_t)3 * 16384,
        b_res + 3 * HIDD, Hh, gamma, beta, W1h, W2p, out);
}